// Round 5
// baseline (411.160 us; speedup 1.0000x reference)
//
#include <hip/hip_runtime.h>
#include <cstdint>

#define NN 4096
#define FIN 512
#define DD 64
#define HH 8
#define CC 16
#define KHOP 2
#define ALPHA 0.2f
#define BETA 0.9f

static __device__ __forceinline__ uint16_t f2bf(float f) {  // RTNE
    uint32_t u = __float_as_uint(f);
    u += 0x7FFFu + ((u >> 16) & 1u);
    return (uint16_t)(u >> 16);
}

// ---------------- build packed bitmask: [K][N][64] u64 (probe fused) ----------------
__global__ __launch_bounds__(256) void build_bits(const uint32_t* __restrict__ mraw,
                                                  uint64_t* __restrict__ bits) {
    const int totalWords = KHOP * NN * (NN / 64);  // 524288
    const int tid = threadIdx.x;
    // inline dtype probe over first 4096 words (16 KB, L2-broadcast across blocks)
    __shared__ int sflag;
    if (tid == 0) sflag = 1;
    __syncthreads();
    bool ok = true;
    for (int i = tid; i < 4096; i += 256) {
        uint32_t w = mraw[i];
        if (!(w == 0u || w == 1u || w == 0x3F800000u)) ok = false;
    }
    if (!ok) sflag = 0;  // benign race: all writers write 0
    __syncthreads();
    const int flag = sflag;

    int gw = (blockIdx.x * 256 + tid) >> 6;
    int lane = tid & 63;
    int nw = (gridDim.x * 256) >> 6;
    if (flag) {  // 4-byte elements (int32 or float32) — nonzero word == true
        for (int w = gw; w < totalWords; w += nw) {
            uint32_t v = __builtin_nontemporal_load(&mraw[(size_t)w * 64 + lane]);
            unsigned long long b = __ballot(v != 0u);
            if (lane == 0) bits[w] = b;
        }
    } else {      // 1-byte bool elements
        const uint8_t* m8 = (const uint8_t*)mraw;
        for (int w = gw; w < totalWords; w += nw) {
            uint8_t v = __builtin_nontemporal_load(&m8[(size_t)w * 64 + lane]);
            unsigned long long b = __ballot(v != 0);
            if (lane == 0) bits[w] = b;
        }
    }
}

// ---------------- layer-1 GEMM: Wh[h,n,d] = x @ W[h]; bf16 out; fused f1/f2 ----------------
// 64n x 64d tile per block; thread tile 4n x 4d. grid (N/64, H), block 256.
__global__ __launch_bounds__(256) void wh_gemm(const float* __restrict__ x,
                                               const float* __restrict__ W,
                                               const float* __restrict__ a1,
                                               const float* __restrict__ a2,
                                               uint16_t* __restrict__ Whb,
                                               float* __restrict__ f1,
                                               float* __restrict__ f2) {
    const int h = blockIdx.y;
    const int n0 = blockIdx.x * 64;
    const int tid = threadIdx.x;
    const int d4 = (tid & 15) * 4;
    const int g = tid >> 4;
    const int nq = g * 4;
    __shared__ float xs[64 * 64];
    float acc[4][4] = {};
    const float* Wp = W + (size_t)h * FIN * DD;

    for (int fc = 0; fc < FIN; fc += 64) {
        {
            const int nl = tid >> 4;
            const int fl = (tid & 15) * 4;
#pragma unroll
            for (int r = 0; r < 4; ++r) {
                const int n = nl + r * 16;
                float4 xv = *(const float4*)&x[(size_t)(n0 + n) * FIN + fc + fl];
                const int ng = n >> 2, nb = n & 3;
                const float xe[4] = {xv.x, xv.y, xv.z, xv.w};
#pragma unroll
                for (int j = 0; j < 4; ++j) {
                    const int k = fl + j;
                    const int cg = ng ^ ((k + (k >> 2)) & 15);
                    xs[k * 64 + cg * 4 + nb] = xe[j];
                }
            }
        }
        __syncthreads();
#pragma unroll 4
        for (int k = 0; k < 64; ++k) {
            const int cg = g ^ ((k + (k >> 2)) & 15);
            float4 xv = *(const float4*)&xs[k * 64 + cg * 4];
            float4 wv = *(const float4*)&Wp[(size_t)(fc + k) * DD + d4];
            acc[0][0] += xv.x * wv.x; acc[0][1] += xv.x * wv.y; acc[0][2] += xv.x * wv.z; acc[0][3] += xv.x * wv.w;
            acc[1][0] += xv.y * wv.x; acc[1][1] += xv.y * wv.y; acc[1][2] += xv.y * wv.z; acc[1][3] += xv.y * wv.w;
            acc[2][0] += xv.z * wv.x; acc[2][1] += xv.z * wv.y; acc[2][2] += xv.z * wv.z; acc[2][3] += xv.z * wv.w;
            acc[3][0] += xv.w * wv.x; acc[3][1] += xv.w * wv.y; acc[3][2] += xv.w * wv.z; acc[3][3] += xv.w * wv.w;
        }
        __syncthreads();
    }

    const int nb0 = n0 + nq;
#pragma unroll
    for (int i = 0; i < 4; ++i) {
        ushort4 o;
        o.x = f2bf(acc[i][0]); o.y = f2bf(acc[i][1]);
        o.z = f2bf(acc[i][2]); o.w = f2bf(acc[i][3]);
        *(ushort4*)&Whb[((size_t)h * NN + nb0 + i) * DD + d4] = o;
    }
    float4 a1v = *(const float4*)&a1[h * DD + d4];
    float4 a2v = *(const float4*)&a2[h * DD + d4];
    float p1[4], p2[4];
#pragma unroll
    for (int i = 0; i < 4; ++i) {
        p1[i] = acc[i][0] * a1v.x + acc[i][1] * a1v.y + acc[i][2] * a1v.z + acc[i][3] * a1v.w;
        p2[i] = acc[i][0] * a2v.x + acc[i][1] * a2v.y + acc[i][2] * a2v.z + acc[i][3] * a2v.w;
#pragma unroll
        for (int off = 1; off < 16; off <<= 1) {
            p1[i] += __shfl_xor(p1[i], off);
            p2[i] += __shfl_xor(p2[i], off);
        }
    }
    if ((tid & 15) == 0) {
#pragma unroll
        for (int i = 0; i < 4; ++i) {
            f1[h * NN + nb0 + i] = p1[i];
            f2[h * NN + nb0 + i] = p2[i];
        }
    }
}

// ---------------- layer-1 attention + fused output GEMM ----------------
// Block per node (512 thr, wave per head). Edges processed 2-at-a-time:
// lanes 0-31 edge j, lanes 32-63 edge j+1; bf16x2 dword loads from Whb.
// Tail: Who row = elu(x2 row) @ W_out + g1/g2, via LDS reduction (all 512 thr!).
__global__ __launch_bounds__(512) void attn1(const uint64_t* __restrict__ bits,
                                             const uint16_t* __restrict__ Whb,
                                             const float* __restrict__ f1,
                                             const float* __restrict__ f2,
                                             const float* __restrict__ Wout,
                                             const float* __restrict__ ao1,
                                             const float* __restrict__ ao2,
                                             float* __restrict__ Who,
                                             float* __restrict__ g1,
                                             float* __restrict__ g2) {
    const int n = blockIdx.x;
    const int tid = threadIdx.x;
    const int h = tid >> 6, lane = tid & 63;
    const int hl = lane & 31, uh = lane >> 5;
    __shared__ uint16_t nbr[NN];      // 8 KB
    __shared__ uint2 wm[HH][64];      // 4 KB per-wave (w, byte-offset) slots
    __shared__ float xrow[HH * DD];   // 2 KB
    __shared__ float part[32][17];    // 2.2 KB
    __shared__ int cnt;
    const float f1n = f1[h * NN + n];
    const float* __restrict__ f2h = f2 + h * NN;
    const char* gbase = (const char*)(Whb + (size_t)h * NN * DD) + hl * 4;
    float res0 = 0.f, res1 = 0.f;
    for (int hop = 0; hop < KHOP; ++hop) {
        __syncthreads();
        if (tid == 0) cnt = 0;
        __syncthreads();
        if (tid < 64) {  // wave 0 extracts set bits of this row's 64 bitmask words
            uint64_t v = bits[((size_t)hop * NN + n) * 64 + tid];
            int c = __popcll(v);
            int base = 0;
            if (c) base = atomicAdd(&cnt, c);
            int mb = tid * 64;
            while (v) {
                int j = __ffsll((unsigned long long)v) - 1;
                nbr[base++] = (uint16_t)(mb + j);
                v &= v - 1;
            }
        }
        __syncthreads();
        const int count = cnt;
        float acc0 = 0.f, acc1 = 0.f, denp = 0.f;
        for (int b0 = 0; b0 < count; b0 += 64) {
            const int bs = min(64, count - b0);
            uint32_t wbits = 0u, moff = 0u;
            if (lane < bs) {
                int m = nbr[b0 + lane];
                float e = f1n + f2h[m];
                e = (e > 0.f) ? e : ALPHA * e;
                float w = __expf(e);
                denp += w;
                wbits = __float_as_uint(w);
                moff = (uint32_t)m << 7;  // byte offset of row m (64 bf16 = 128 B)
            }
            wm[h][lane] = make_uint2(wbits, moff);
            const int bsp = (bs + 1) & ~1;
            for (int j0 = 0; j0 < bsp; j0 += 4) {
#pragma unroll
                for (int jj = 0; jj < 4; jj += 2) {
                    const int j = j0 + jj;
                    if (j >= bsp) break;
                    uint2 wmv = wm[h][j + uh];
                    float w = __uint_as_float(wmv.x);
                    uint32_t dv = *(const uint32_t*)(gbase + wmv.y);
                    float lo = __uint_as_float(dv << 16);
                    float hi = __uint_as_float(dv & 0xFFFF0000u);
                    acc0 += w * lo;
                    acc1 += w * hi;
                }
            }
        }
        float den = denp;
#pragma unroll
        for (int off = 1; off < 64; off <<= 1) den += __shfl_xor(den, off);
        acc0 += __shfl_xor(acc0, 32);
        acc1 += __shfl_xor(acc1, 32);
        const float scale = ((hop == 0) ? 1.f : BETA) / den;
        res0 += scale * acc0;
        res1 += scale * acc1;
    }
    // elu, stash x2 row in LDS (lane hl covers d = 2*hl, 2*hl+1)
    float v0 = (res0 > 0.f) ? res0 : (__expf(res0) - 1.f);
    float v1 = (res1 > 0.f) ? res1 : (__expf(res1) - 1.f);
    if (uh == 0) {
        xrow[h * DD + 2 * hl]     = v0;
        xrow[h * DD + 2 * hl + 1] = v1;
    }
    __syncthreads();
    // Who[n,c] = sum_t xrow[t] * Wout[t,c] — ALL 512 threads: chunk 0..31 covers t=0..511
    {
        const int c = tid & 15, chunk = tid >> 4;
        float p = 0.f;
#pragma unroll
        for (int i = 0; i < 16; ++i)
            p += xrow[chunk * 16 + i] * Wout[(chunk * 16 + i) * CC + c];
        part[chunk][c] = p;
    }
    __syncthreads();
    if (tid < 16) {
        float s = 0.f;
#pragma unroll
        for (int k = 0; k < 32; ++k) s += part[k][tid];
        Who[n * CC + tid] = s;
        float p1 = s * ao1[tid];
        float p2 = s * ao2[tid];
#pragma unroll
        for (int off = 1; off < 16; off <<= 1) {
            p1 += __shfl_xor(p1, off);
            p2 += __shfl_xor(p2, off);
        }
        if (tid == 0) { g1[n] = p1; g2[n] = p2; }
    }
}

// ---------------- layer-2 attention + elu + log_softmax: one wave per node ----------------
__global__ __launch_bounds__(256) void attn2(const uint64_t* __restrict__ bits,
                                             const float* __restrict__ Who,
                                             const float* __restrict__ g1,
                                             const float* __restrict__ g2,
                                             float* __restrict__ out) {
    const int wv = threadIdx.x >> 6;
    const int lane = threadIdx.x & 63;
    const int n = blockIdx.x * 4 + wv;
    __shared__ uint16_t nbr[4][NN];  // per-wave neighbor list
    uint16_t* mynbr = nbr[wv];
    const float g1n = g1[n];
    const int c = lane & 15, s = lane >> 4;  // 16 classes x 4-way m-parallel
    float res = 0.f;
    for (int hop = 0; hop < KHOP; ++hop) {
        uint64_t v = bits[((size_t)hop * NN + n) * 64 + lane];
        int cpc = __popcll(v);
        int pref = cpc;  // inclusive prefix sum across wave
        for (int off = 1; off < 64; off <<= 1) {
            int t = __shfl_up(pref, off);
            if (lane >= off) pref += t;
        }
        int total = __shfl(pref, 63);
        int base = pref - cpc;
        int mb = lane * 64;
        while (v) {
            int j = __ffsll((unsigned long long)v) - 1;
            mynbr[base++] = (uint16_t)(mb + j);
            v &= v - 1;
        }
        __syncthreads();
        float acc = 0.f, den = 0.f;
        for (int j = s; j < total; j += 4) {
            int m = mynbr[j];
            float e = g1n + g2[m];
            e = (e > 0.f) ? e : ALPHA * e;
            float w = __expf(e);
            den += w;
            acc += w * Who[m * CC + c];
        }
        acc += __shfl_xor(acc, 16);
        acc += __shfl_xor(acc, 32);
        den += __shfl_xor(den, 16);
        den += __shfl_xor(den, 32);
        res += ((hop == 0) ? 1.f : BETA) * (acc / den);
        __syncthreads();
    }
    float o = (res > 0.f) ? res : (__expf(res) - 1.f);  // elu
    float mx = o;
    for (int off = 1; off < 16; off <<= 1) mx = fmaxf(mx, __shfl_xor(mx, off));
    float ex = __expf(o - mx);
    float sum = ex;
    for (int off = 1; off < 16; off <<= 1) sum += __shfl_xor(sum, off);
    float r = o - mx - __logf(sum);
    if (lane < 16) out[n * CC + c] = r;
}

extern "C" void kernel_launch(void* const* d_in, const int* in_sizes, int n_in,
                              void* d_out, int out_size, void* d_ws, size_t ws_size,
                              hipStream_t stream) {
    const float* x    = (const float*)d_in[0];
    const void*  masks= d_in[1];
    const float* W    = (const float*)d_in[2];
    const float* a1   = (const float*)d_in[3];
    const float* a2   = (const float*)d_in[4];
    const float* Wout = (const float*)d_in[5];
    const float* ao1  = (const float*)d_in[6];
    const float* ao2  = (const float*)d_in[7];
    float* out = (float*)d_out;

    char* ws = (char*)d_ws;
    uint64_t* bits = (uint64_t*)ws;                         // 4 MB
    uint16_t* Whb  = (uint16_t*)(ws + (size_t)KHOP * NN * 64 * 8);  // 4 MB (bf16)
    float* f1  = (float*)(Whb + (size_t)HH * NN * DD);      // 128 KB
    float* f2  = f1 + (size_t)HH * NN;                      // 128 KB
    float* Who = f2 + (size_t)HH * NN;                      // 256 KB
    float* g1  = Who + (size_t)NN * CC;                     // 16 KB
    float* g2  = g1 + NN;                                   // 16 KB

    build_bits<<<1024, 256, 0, stream>>>((const uint32_t*)masks, bits);
    wh_gemm<<<dim3(NN / 64, HH), 256, 0, stream>>>(x, W, a1, a2, Whb, f1, f2);
    attn1<<<NN, 512, 0, stream>>>(bits, Whb, f1, f2, Wout, ao1, ao2, Who, g1, g2);
    attn2<<<NN / 4, 256, 0, stream>>>(bits, Who, g1, g2, out);
    (void)in_sizes; (void)n_in; (void)out_size; (void)ws_size;
}

// Round 6
// 384.995 us; speedup vs baseline: 1.0680x; 1.0680x over previous
//
#include <hip/hip_runtime.h>
#include <cstdint>

#define NN 4096
#define FIN 512
#define DD 64
#define HH 8
#define CC 16
#define KHOP 2
#define ALPHA 0.2f
#define BETA 0.9f

static __device__ __forceinline__ uint16_t f2bf(float f) {  // RTNE
    uint32_t u = __float_as_uint(f);
    u += 0x7FFFu + ((u >> 16) & 1u);
    return (uint16_t)(u >> 16);
}

// ---------------- build packed bitmask: [K][N][64] u64 (probe fused) ----------------
__global__ __launch_bounds__(256) void build_bits(const uint32_t* __restrict__ mraw,
                                                  uint64_t* __restrict__ bits) {
    const int totalWords = KHOP * NN * (NN / 64);  // 524288
    const int tid = threadIdx.x;
    __shared__ int sflag;
    if (tid == 0) sflag = 1;
    __syncthreads();
    bool ok = true;
    for (int i = tid; i < 4096; i += 256) {
        uint32_t w = mraw[i];
        if (!(w == 0u || w == 1u || w == 0x3F800000u)) ok = false;
    }
    if (!ok) sflag = 0;  // benign race: all writers write 0
    __syncthreads();
    const int flag = sflag;

    int gw = (blockIdx.x * 256 + tid) >> 6;
    int lane = tid & 63;
    int nw = (gridDim.x * 256) >> 6;
    if (flag) {  // 4-byte elements (int32 or float32) — nonzero word == true
        for (int w = gw; w < totalWords; w += nw) {
            uint32_t v = __builtin_nontemporal_load(&mraw[(size_t)w * 64 + lane]);
            unsigned long long b = __ballot(v != 0u);
            if (lane == 0) bits[w] = b;
        }
    } else {      // 1-byte bool elements
        const uint8_t* m8 = (const uint8_t*)mraw;
        for (int w = gw; w < totalWords; w += nw) {
            uint8_t v = __builtin_nontemporal_load(&m8[(size_t)w * 64 + lane]);
            unsigned long long b = __ballot(v != 0);
            if (lane == 0) bits[w] = b;
        }
    }
}

// ---------------- layer-1 GEMM: Wh[h,n,d] = x @ W[h]; bf16 out; fused f1/f2 ----------------
__global__ __launch_bounds__(256) void wh_gemm(const float* __restrict__ x,
                                               const float* __restrict__ W,
                                               const float* __restrict__ a1,
                                               const float* __restrict__ a2,
                                               uint16_t* __restrict__ Whb,
                                               float* __restrict__ f1,
                                               float* __restrict__ f2) {
    const int h = blockIdx.y;
    const int n0 = blockIdx.x * 64;
    const int tid = threadIdx.x;
    const int d4 = (tid & 15) * 4;
    const int g = tid >> 4;
    const int nq = g * 4;
    __shared__ float xs[64 * 64];
    float acc[4][4] = {};
    const float* Wp = W + (size_t)h * FIN * DD;

    for (int fc = 0; fc < FIN; fc += 64) {
        {
            const int nl = tid >> 4;
            const int fl = (tid & 15) * 4;
#pragma unroll
            for (int r = 0; r < 4; ++r) {
                const int n = nl + r * 16;
                float4 xv = *(const float4*)&x[(size_t)(n0 + n) * FIN + fc + fl];
                const int ng = n >> 2, nb = n & 3;
                const float xe[4] = {xv.x, xv.y, xv.z, xv.w};
#pragma unroll
                for (int j = 0; j < 4; ++j) {
                    const int k = fl + j;
                    const int cg = ng ^ ((k + (k >> 2)) & 15);
                    xs[k * 64 + cg * 4 + nb] = xe[j];
                }
            }
        }
        __syncthreads();
#pragma unroll 4
        for (int k = 0; k < 64; ++k) {
            const int cg = g ^ ((k + (k >> 2)) & 15);
            float4 xv = *(const float4*)&xs[k * 64 + cg * 4];
            float4 wv = *(const float4*)&Wp[(size_t)(fc + k) * DD + d4];
            acc[0][0] += xv.x * wv.x; acc[0][1] += xv.x * wv.y; acc[0][2] += xv.x * wv.z; acc[0][3] += xv.x * wv.w;
            acc[1][0] += xv.y * wv.x; acc[1][1] += xv.y * wv.y; acc[1][2] += xv.y * wv.z; acc[1][3] += xv.y * wv.w;
            acc[2][0] += xv.z * wv.x; acc[2][1] += xv.z * wv.y; acc[2][2] += xv.z * wv.z; acc[2][3] += xv.z * wv.w;
            acc[3][0] += xv.w * wv.x; acc[3][1] += xv.w * wv.y; acc[3][2] += xv.w * wv.z; acc[3][3] += xv.w * wv.w;
        }
        __syncthreads();
    }

    const int nb0 = n0 + nq;
#pragma unroll
    for (int i = 0; i < 4; ++i) {
        ushort4 o;
        o.x = f2bf(acc[i][0]); o.y = f2bf(acc[i][1]);
        o.z = f2bf(acc[i][2]); o.w = f2bf(acc[i][3]);
        *(ushort4*)&Whb[((size_t)h * NN + nb0 + i) * DD + d4] = o;
    }
    float4 a1v = *(const float4*)&a1[h * DD + d4];
    float4 a2v = *(const float4*)&a2[h * DD + d4];
    float p1[4], p2[4];
#pragma unroll
    for (int i = 0; i < 4; ++i) {
        p1[i] = acc[i][0] * a1v.x + acc[i][1] * a1v.y + acc[i][2] * a1v.z + acc[i][3] * a1v.w;
        p2[i] = acc[i][0] * a2v.x + acc[i][1] * a2v.y + acc[i][2] * a2v.z + acc[i][3] * a2v.w;
#pragma unroll
        for (int off = 1; off < 16; off <<= 1) {
            p1[i] += __shfl_xor(p1[i], off);
            p2[i] += __shfl_xor(p2[i], off);
        }
    }
    if ((tid & 15) == 0) {
#pragma unroll
        for (int i = 0; i < 4; ++i) {
            f1[h * NN + nb0 + i] = p1[i];
            f2[h * NN + nb0 + i] = p2[i];
        }
    }
}

// ---------------- layer-1 attention + fused output GEMM ----------------
// Block per node (512 thr, wave per head). Both hop lists extracted upfront by
// waves 0/1. Edge pairs: lanes 0-31 edge j, lanes 32-63 edge j+1; (w, rowoff)
// broadcast via v_readlane (registers, no LDS in address chain); 8 loads in
// flight per 16-edge chunk; pad edges are branchless w=0/row-0.
__global__ __launch_bounds__(512) void attn1(const uint64_t* __restrict__ bits,
                                             const uint16_t* __restrict__ Whb,
                                             const float* __restrict__ f1,
                                             const float* __restrict__ f2,
                                             const float* __restrict__ Wout,
                                             const float* __restrict__ ao1,
                                             const float* __restrict__ ao2,
                                             float* __restrict__ Who,
                                             float* __restrict__ g1,
                                             float* __restrict__ g2) {
    const int n = blockIdx.x;
    const int tid = threadIdx.x;
    const int h = tid >> 6, lane = tid & 63;
    const int hl = lane & 31, uh = lane >> 5;
    __shared__ uint16_t nbr[KHOP][NN];  // 16 KB worst case
    __shared__ float xrow[HH * DD];     // 2 KB
    __shared__ float part[32][17];      // 2.2 KB
    __shared__ int cnt[KHOP];
    // parallel extraction: wave `hop` builds list for hop `hop`
    if (h < KHOP) {
        const int hop = h;
        if (lane == 0) cnt[hop] = 0;    // same-wave LDS ops are ordered; safe
        uint64_t v = bits[((size_t)hop * NN + n) * 64 + lane];
        int c = __popcll(v);
        int base = 0;
        if (c) base = atomicAdd(&cnt[hop], c);
        int mb = lane * 64;
        while (v) {
            int j = __ffsll((unsigned long long)v) - 1;
            nbr[hop][base++] = (uint16_t)(mb + j);
            v &= v - 1;
        }
    }
    const float f1n = f1[h * NN + n];
    const float* __restrict__ f2h = f2 + h * NN;
    const char* gbase = (const char*)(Whb + (size_t)h * NN * DD) + hl * 4;
    __syncthreads();
    float res0 = 0.f, res1 = 0.f;
    for (int hop = 0; hop < KHOP; ++hop) {
        const int count = cnt[hop];
        const uint16_t* __restrict__ nb = nbr[hop];
        float acc0 = 0.f, acc1 = 0.f, denp = 0.f;
        for (int b0 = 0; b0 < count; b0 += 64) {
            const int bs = min(64, count - b0);
            uint32_t moff = 0u; float w = 0.f;
            if (lane < bs) {
                int m = nb[b0 + lane];
                float e = f1n + f2h[m];
                e = (e > 0.f) ? e : ALPHA * e;
                w = __expf(e);
                moff = (uint32_t)m << 7;  // byte offset of 128-B bf16 row
            }
            denp += w;
            const int nch = (bs + 15) >> 4;
            for (int c0 = 0; c0 < nch; ++c0) {
                const int jb = c0 << 4;
#pragma unroll
                for (int p = 0; p < 8; ++p) {
                    const int j = jb + 2 * p;
                    const uint32_t wu0 = __builtin_amdgcn_readlane(__float_as_uint(w), j);
                    const uint32_t wu1 = __builtin_amdgcn_readlane(__float_as_uint(w), j + 1);
                    const uint32_t o0 = __builtin_amdgcn_readlane(moff, j);
                    const uint32_t o1 = __builtin_amdgcn_readlane(moff, j + 1);
                    const float wsel = __uint_as_float(uh ? wu1 : wu0);
                    const uint32_t osel = uh ? o1 : o0;
                    const uint32_t dv = *(const uint32_t*)(gbase + osel);
                    acc0 += wsel * __uint_as_float(dv << 16);
                    acc1 += wsel * __uint_as_float(dv & 0xFFFF0000u);
                }
            }
        }
        float den = denp;
#pragma unroll
        for (int off = 1; off < 64; off <<= 1) den += __shfl_xor(den, off);
        acc0 += __shfl_xor(acc0, 32);
        acc1 += __shfl_xor(acc1, 32);
        const float scale = ((hop == 0) ? 1.f : BETA) / den;
        res0 += scale * acc0;
        res1 += scale * acc1;
    }
    // elu, stash x2 row in LDS (lane hl covers d = 2*hl, 2*hl+1)
    float v0 = (res0 > 0.f) ? res0 : (__expf(res0) - 1.f);
    float v1 = (res1 > 0.f) ? res1 : (__expf(res1) - 1.f);
    if (uh == 0) {
        xrow[h * DD + 2 * hl]     = v0;
        xrow[h * DD + 2 * hl + 1] = v1;
    }
    __syncthreads();
    // Who[n,c] = sum_t xrow[t] * Wout[t,c] — all 512 threads: chunk 0..31 covers t=0..511
    {
        const int c = tid & 15, chunk = tid >> 4;
        float p = 0.f;
#pragma unroll
        for (int i = 0; i < 16; ++i)
            p += xrow[chunk * 16 + i] * Wout[(chunk * 16 + i) * CC + c];
        part[chunk][c] = p;
    }
    __syncthreads();
    if (tid < 16) {
        float s = 0.f;
#pragma unroll
        for (int k = 0; k < 32; ++k) s += part[k][tid];
        Who[n * CC + tid] = s;
        float p1 = s * ao1[tid];
        float p2 = s * ao2[tid];
#pragma unroll
        for (int off = 1; off < 16; off <<= 1) {
            p1 += __shfl_xor(p1, off);
            p2 += __shfl_xor(p2, off);
        }
        if (tid == 0) { g1[n] = p1; g2[n] = p2; }
    }
}

// ---------------- layer-2 attention + elu + log_softmax: one wave per node ----------------
__global__ __launch_bounds__(256) void attn2(const uint64_t* __restrict__ bits,
                                             const float* __restrict__ Who,
                                             const float* __restrict__ g1,
                                             const float* __restrict__ g2,
                                             float* __restrict__ out) {
    const int wv = threadIdx.x >> 6;
    const int lane = threadIdx.x & 63;
    const int n = blockIdx.x * 4 + wv;
    __shared__ uint16_t nbr[4][NN];  // per-wave neighbor list
    uint16_t* mynbr = nbr[wv];
    const float g1n = g1[n];
    const int c = lane & 15, s = lane >> 4;  // 16 classes x 4-way m-parallel
    float res = 0.f;
    for (int hop = 0; hop < KHOP; ++hop) {
        uint64_t v = bits[((size_t)hop * NN + n) * 64 + lane];
        int cpc = __popcll(v);
        int pref = cpc;  // inclusive prefix sum across wave
        for (int off = 1; off < 64; off <<= 1) {
            int t = __shfl_up(pref, off);
            if (lane >= off) pref += t;
        }
        int total = __shfl(pref, 63);
        int base = pref - cpc;
        int mb = lane * 64;
        while (v) {
            int j = __ffsll((unsigned long long)v) - 1;
            mynbr[base++] = (uint16_t)(mb + j);
            v &= v - 1;
        }
        __syncthreads();
        float acc = 0.f, den = 0.f;
        for (int j = s; j < total; j += 4) {
            int m = mynbr[j];
            float e = g1n + g2[m];
            e = (e > 0.f) ? e : ALPHA * e;
            float w = __expf(e);
            den += w;
            acc += w * Who[m * CC + c];
        }
        acc += __shfl_xor(acc, 16);
        acc += __shfl_xor(acc, 32);
        den += __shfl_xor(den, 16);
        den += __shfl_xor(den, 32);
        res += ((hop == 0) ? 1.f : BETA) * (acc / den);
        __syncthreads();
    }
    float o = (res > 0.f) ? res : (__expf(res) - 1.f);  // elu
    float mx = o;
    for (int off = 1; off < 16; off <<= 1) mx = fmaxf(mx, __shfl_xor(mx, off));
    float ex = __expf(o - mx);
    float sum = ex;
    for (int off = 1; off < 16; off <<= 1) sum += __shfl_xor(sum, off);
    float r = o - mx - __logf(sum);
    if (lane < 16) out[n * CC + c] = r;
}

extern "C" void kernel_launch(void* const* d_in, const int* in_sizes, int n_in,
                              void* d_out, int out_size, void* d_ws, size_t ws_size,
                              hipStream_t stream) {
    const float* x    = (const float*)d_in[0];
    const void*  masks= d_in[1];
    const float* W    = (const float*)d_in[2];
    const float* a1   = (const float*)d_in[3];
    const float* a2   = (const float*)d_in[4];
    const float* Wout = (const float*)d_in[5];
    const float* ao1  = (const float*)d_in[6];
    const float* ao2  = (const float*)d_in[7];
    float* out = (float*)d_out;

    char* ws = (char*)d_ws;
    uint64_t* bits = (uint64_t*)ws;                         // 4 MB
    uint16_t* Whb  = (uint16_t*)(ws + (size_t)KHOP * NN * 64 * 8);  // 4 MB (bf16)
    float* f1  = (float*)(Whb + (size_t)HH * NN * DD);      // 128 KB
    float* f2  = f1 + (size_t)HH * NN;                      // 128 KB
    float* Who = f2 + (size_t)HH * NN;                      // 256 KB
    float* g1  = Who + (size_t)NN * CC;                     // 16 KB
    float* g2  = g1 + NN;                                   // 16 KB

    build_bits<<<1024, 256, 0, stream>>>((const uint32_t*)masks, bits);
    wh_gemm<<<dim3(NN / 64, HH), 256, 0, stream>>>(x, W, a1, a2, Whb, f1, f2);
    attn1<<<NN, 512, 0, stream>>>(bits, Whb, f1, f2, Wout, ao1, ao2, Who, g1, g2);
    attn2<<<NN / 4, 256, 0, stream>>>(bits, Who, g1, g2, out);
    (void)in_sizes; (void)n_in; (void)out_size; (void)ws_size;
}

// Round 7
// 345.323 us; speedup vs baseline: 1.1907x; 1.1149x over previous
//
#include <hip/hip_runtime.h>
#include <cstdint>

#define NN 4096
#define FIN 512
#define DD 64
#define HH 8
#define CC 16
#define KHOP 2
#define ALPHA 0.2f
#define BETA 0.9f

static __device__ __forceinline__ uint16_t f2bf(float f) {  // RTNE
    uint32_t u = __float_as_uint(f);
    u += 0x7FFFu + ((u >> 16) & 1u);
    return (uint16_t)(u >> 16);
}

// nonzero-byte nibble: bit i set iff byte i of x is nonzero (verified bit algebra)
static __device__ __forceinline__ uint32_t nz_nib(uint32_t x) {
    uint32_t zero80 = (x - 0x01010101u) & ~x & 0x80808080u;  // 0x80 where byte==0
    uint32_t nz80 = zero80 ^ 0x80808080u;                    // 0x80 where byte!=0
    return ((nz80 >> 7) * 0x01020408u) >> 24;                // bits 0..3
}

// ---------------- build packed bitmask: [K][N][64] u64 (probe fused) ----------------
// Bool path: lane loads uint4 (16 B); wave iteration = 1024 B = 16 output words.
// 8 iterations/wave, all loads issued up front (8 in flight).
__global__ __launch_bounds__(256) void build_bits(const uint32_t* __restrict__ mraw,
                                                  uint64_t* __restrict__ bits) {
    const int totalWords = KHOP * NN * (NN / 64);  // 524288
    const int tid = threadIdx.x;
    __shared__ int sflag;
    if (tid == 0) sflag = 1;
    __syncthreads();
    bool ok = true;
    for (int i = tid; i < 4096; i += 256) {
        uint32_t w = mraw[i];
        if (!(w == 0u || w == 1u || w == 0x3F800000u)) ok = false;
    }
    if (!ok) sflag = 0;  // benign race: all writers write 0
    __syncthreads();
    const int flag = sflag;

    const int wave_id = (blockIdx.x * 256 + tid) >> 6;  // grid 1024x256 -> 4096 waves
    const int lane = tid & 63;

    if (!flag) {  // 1-byte bool elements (the observed case)
        const uint8_t* m8 = (const uint8_t*)mraw;
        // wave covers words [wave_id*128, wave_id*128+128), 16 words/iter, 8 iters
        const uint8_t* base = m8 + (size_t)wave_id * 8192 + (size_t)lane * 16;
        uint4 v[8];
#pragma unroll
        for (int i = 0; i < 8; ++i)
            v[i] = *(const uint4*)(base + (size_t)i * 1024);
        const int idx = (lane & 15) * 4;
#pragma unroll
        for (int i = 0; i < 8; ++i) {
            uint32_t m16 = nz_nib(v[i].x) | (nz_nib(v[i].y) << 4) |
                           (nz_nib(v[i].z) << 8) | (nz_nib(v[i].w) << 12);
            uint32_t u0 = (uint32_t)__shfl((int)m16, idx);
            uint32_t u1 = (uint32_t)__shfl((int)m16, idx + 1);
            uint32_t u2 = (uint32_t)__shfl((int)m16, idx + 2);
            uint32_t u3 = (uint32_t)__shfl((int)m16, idx + 3);
            if (lane < 16) {
                uint64_t wrd = (uint64_t)((u0 & 0xFFFFu) | (u1 << 16)) |
                               ((uint64_t)((u2 & 0xFFFFu) | (u3 << 16)) << 32);
                bits[(size_t)wave_id * 128 + i * 16 + lane] = wrd;
            }
        }
    } else {  // 4-byte elements (int32/float32): ballot path, 8-deep unroll
        const int w0b = wave_id * 128;
        for (int w0 = w0b; w0 < w0b + 128 && w0 < totalWords; w0 += 8) {
            uint32_t v[8];
#pragma unroll
            for (int i = 0; i < 8; ++i)
                v[i] = mraw[(size_t)(w0 + i) * 64 + lane];
#pragma unroll
            for (int i = 0; i < 8; ++i) {
                unsigned long long b = __ballot(v[i] != 0u);
                if (lane == 0) bits[w0 + i] = b;
            }
        }
    }
}

// ---------------- layer-1 GEMM: Wh[h,n,d] = x @ W[h]; bf16 out; fused f1/f2 ----------------
__global__ __launch_bounds__(256) void wh_gemm(const float* __restrict__ x,
                                               const float* __restrict__ W,
                                               const float* __restrict__ a1,
                                               const float* __restrict__ a2,
                                               uint16_t* __restrict__ Whb,
                                               float* __restrict__ f1,
                                               float* __restrict__ f2) {
    const int h = blockIdx.y;
    const int n0 = blockIdx.x * 64;
    const int tid = threadIdx.x;
    const int d4 = (tid & 15) * 4;
    const int g = tid >> 4;
    const int nq = g * 4;
    __shared__ float xs[64 * 64];
    float acc[4][4] = {};
    const float* Wp = W + (size_t)h * FIN * DD;

    for (int fc = 0; fc < FIN; fc += 64) {
        {
            const int nl = tid >> 4;
            const int fl = (tid & 15) * 4;
#pragma unroll
            for (int r = 0; r < 4; ++r) {
                const int n = nl + r * 16;
                float4 xv = *(const float4*)&x[(size_t)(n0 + n) * FIN + fc + fl];
                const int ng = n >> 2, nb = n & 3;
                const float xe[4] = {xv.x, xv.y, xv.z, xv.w};
#pragma unroll
                for (int j = 0; j < 4; ++j) {
                    const int k = fl + j;
                    const int cg = ng ^ ((k + (k >> 2)) & 15);
                    xs[k * 64 + cg * 4 + nb] = xe[j];
                }
            }
        }
        __syncthreads();
#pragma unroll 4
        for (int k = 0; k < 64; ++k) {
            const int cg = g ^ ((k + (k >> 2)) & 15);
            float4 xv = *(const float4*)&xs[k * 64 + cg * 4];
            float4 wv = *(const float4*)&Wp[(size_t)(fc + k) * DD + d4];
            acc[0][0] += xv.x * wv.x; acc[0][1] += xv.x * wv.y; acc[0][2] += xv.x * wv.z; acc[0][3] += xv.x * wv.w;
            acc[1][0] += xv.y * wv.x; acc[1][1] += xv.y * wv.y; acc[1][2] += xv.y * wv.z; acc[1][3] += xv.y * wv.w;
            acc[2][0] += xv.z * wv.x; acc[2][1] += xv.z * wv.y; acc[2][2] += xv.z * wv.z; acc[2][3] += xv.z * wv.w;
            acc[3][0] += xv.w * wv.x; acc[3][1] += xv.w * wv.y; acc[3][2] += xv.w * wv.z; acc[3][3] += xv.w * wv.w;
        }
        __syncthreads();
    }

    const int nb0 = n0 + nq;
#pragma unroll
    for (int i = 0; i < 4; ++i) {
        ushort4 o;
        o.x = f2bf(acc[i][0]); o.y = f2bf(acc[i][1]);
        o.z = f2bf(acc[i][2]); o.w = f2bf(acc[i][3]);
        *(ushort4*)&Whb[((size_t)h * NN + nb0 + i) * DD + d4] = o;
    }
    float4 a1v = *(const float4*)&a1[h * DD + d4];
    float4 a2v = *(const float4*)&a2[h * DD + d4];
    float p1[4], p2[4];
#pragma unroll
    for (int i = 0; i < 4; ++i) {
        p1[i] = acc[i][0] * a1v.x + acc[i][1] * a1v.y + acc[i][2] * a1v.z + acc[i][3] * a1v.w;
        p2[i] = acc[i][0] * a2v.x + acc[i][1] * a2v.y + acc[i][2] * a2v.z + acc[i][3] * a2v.w;
#pragma unroll
        for (int off = 1; off < 16; off <<= 1) {
            p1[i] += __shfl_xor(p1[i], off);
            p2[i] += __shfl_xor(p2[i], off);
        }
    }
    if ((tid & 15) == 0) {
#pragma unroll
        for (int i = 0; i < 4; ++i) {
            f1[h * NN + nb0 + i] = p1[i];
            f2[h * NN + nb0 + i] = p2[i];
        }
    }
}

// ---------------- layer-1 attention + fused output GEMM ----------------
__global__ __launch_bounds__(512) void attn1(const uint64_t* __restrict__ bits,
                                             const uint16_t* __restrict__ Whb,
                                             const float* __restrict__ f1,
                                             const float* __restrict__ f2,
                                             const float* __restrict__ Wout,
                                             const float* __restrict__ ao1,
                                             const float* __restrict__ ao2,
                                             float* __restrict__ Who,
                                             float* __restrict__ g1,
                                             float* __restrict__ g2) {
    const int n = blockIdx.x;
    const int tid = threadIdx.x;
    const int h = tid >> 6, lane = tid & 63;
    const int hl = lane & 31, uh = lane >> 5;
    __shared__ uint16_t nbr[KHOP][NN];  // 16 KB worst case
    __shared__ float xrow[HH * DD];     // 2 KB
    __shared__ float part[32][17];      // 2.2 KB
    __shared__ int cnt[KHOP];
    // parallel extraction: wave `hop` builds list for hop `hop`
    if (h < KHOP) {
        const int hop = h;
        if (lane == 0) cnt[hop] = 0;    // same-wave LDS ops are ordered; safe
        uint64_t v = bits[((size_t)hop * NN + n) * 64 + lane];
        int c = __popcll(v);
        int base = 0;
        if (c) base = atomicAdd(&cnt[hop], c);
        int mb = lane * 64;
        while (v) {
            int j = __ffsll((unsigned long long)v) - 1;
            nbr[hop][base++] = (uint16_t)(mb + j);
            v &= v - 1;
        }
    }
    const float f1n = f1[h * NN + n];
    const float* __restrict__ f2h = f2 + h * NN;
    const char* gbase = (const char*)(Whb + (size_t)h * NN * DD) + hl * 4;
    __syncthreads();
    float res0 = 0.f, res1 = 0.f;
    for (int hop = 0; hop < KHOP; ++hop) {
        const int count = cnt[hop];
        const uint16_t* __restrict__ nb = nbr[hop];
        float acc0 = 0.f, acc1 = 0.f, denp = 0.f;
        for (int b0 = 0; b0 < count; b0 += 64) {
            const int bs = min(64, count - b0);
            uint32_t moff = 0u; float w = 0.f;
            if (lane < bs) {
                int m = nb[b0 + lane];
                float e = f1n + f2h[m];
                e = (e > 0.f) ? e : ALPHA * e;
                w = __expf(e);
                moff = (uint32_t)m << 7;  // byte offset of 128-B bf16 row
            }
            denp += w;
            const int nch = (bs + 15) >> 4;
            for (int c0 = 0; c0 < nch; ++c0) {
                const int jb = c0 << 4;
#pragma unroll
                for (int p = 0; p < 8; ++p) {
                    const int j = jb + 2 * p;
                    const uint32_t wu0 = __builtin_amdgcn_readlane(__float_as_uint(w), j);
                    const uint32_t wu1 = __builtin_amdgcn_readlane(__float_as_uint(w), j + 1);
                    const uint32_t o0 = __builtin_amdgcn_readlane(moff, j);
                    const uint32_t o1 = __builtin_amdgcn_readlane(moff, j + 1);
                    const float wsel = __uint_as_float(uh ? wu1 : wu0);
                    const uint32_t osel = uh ? o1 : o0;
                    const uint32_t dv = *(const uint32_t*)(gbase + osel);
                    acc0 += wsel * __uint_as_float(dv << 16);
                    acc1 += wsel * __uint_as_float(dv & 0xFFFF0000u);
                }
            }
        }
        float den = denp;
#pragma unroll
        for (int off = 1; off < 64; off <<= 1) den += __shfl_xor(den, off);
        acc0 += __shfl_xor(acc0, 32);
        acc1 += __shfl_xor(acc1, 32);
        const float scale = ((hop == 0) ? 1.f : BETA) / den;
        res0 += scale * acc0;
        res1 += scale * acc1;
    }
    // elu, stash x2 row in LDS (lane hl covers d = 2*hl, 2*hl+1)
    float v0 = (res0 > 0.f) ? res0 : (__expf(res0) - 1.f);
    float v1 = (res1 > 0.f) ? res1 : (__expf(res1) - 1.f);
    if (uh == 0) {
        xrow[h * DD + 2 * hl]     = v0;
        xrow[h * DD + 2 * hl + 1] = v1;
    }
    __syncthreads();
    // Who[n,c] = sum_t xrow[t] * Wout[t,c] — all 512 threads: chunk 0..31 covers t=0..511
    {
        const int c = tid & 15, chunk = tid >> 4;
        float p = 0.f;
#pragma unroll
        for (int i = 0; i < 16; ++i)
            p += xrow[chunk * 16 + i] * Wout[(chunk * 16 + i) * CC + c];
        part[chunk][c] = p;
    }
    __syncthreads();
    if (tid < 16) {
        float s = 0.f;
#pragma unroll
        for (int k = 0; k < 32; ++k) s += part[k][tid];
        Who[n * CC + tid] = s;
        float p1 = s * ao1[tid];
        float p2 = s * ao2[tid];
#pragma unroll
        for (int off = 1; off < 16; off <<= 1) {
            p1 += __shfl_xor(p1, off);
            p2 += __shfl_xor(p2, off);
        }
        if (tid == 0) { g1[n] = p1; g2[n] = p2; }
    }
}

// ---------------- layer-2 attention + elu + log_softmax: one wave per node ----------------
__global__ __launch_bounds__(256) void attn2(const uint64_t* __restrict__ bits,
                                             const float* __restrict__ Who,
                                             const float* __restrict__ g1,
                                             const float* __restrict__ g2,
                                             float* __restrict__ out) {
    const int wv = threadIdx.x >> 6;
    const int lane = threadIdx.x & 63;
    const int n = blockIdx.x * 4 + wv;
    __shared__ uint16_t nbr[4][NN];  // per-wave neighbor list
    uint16_t* mynbr = nbr[wv];
    const float g1n = g1[n];
    const int c = lane & 15, s = lane >> 4;  // 16 classes x 4-way m-parallel
    float res = 0.f;
    for (int hop = 0; hop < KHOP; ++hop) {
        uint64_t v = bits[((size_t)hop * NN + n) * 64 + lane];
        int cpc = __popcll(v);
        int pref = cpc;  // inclusive prefix sum across wave
        for (int off = 1; off < 64; off <<= 1) {
            int t = __shfl_up(pref, off);
            if (lane >= off) pref += t;
        }
        int total = __shfl(pref, 63);
        int base = pref - cpc;
        int mb = lane * 64;
        while (v) {
            int j = __ffsll((unsigned long long)v) - 1;
            mynbr[base++] = (uint16_t)(mb + j);
            v &= v - 1;
        }
        __syncthreads();
        float acc = 0.f, den = 0.f;
        for (int j = s; j < total; j += 4) {
            int m = mynbr[j];
            float e = g1n + g2[m];
            e = (e > 0.f) ? e : ALPHA * e;
            float w = __expf(e);
            den += w;
            acc += w * Who[m * CC + c];
        }
        acc += __shfl_xor(acc, 16);
        acc += __shfl_xor(acc, 32);
        den += __shfl_xor(den, 16);
        den += __shfl_xor(den, 32);
        res += ((hop == 0) ? 1.f : BETA) * (acc / den);
        __syncthreads();
    }
    float o = (res > 0.f) ? res : (__expf(res) - 1.f);  // elu
    float mx = o;
    for (int off = 1; off < 16; off <<= 1) mx = fmaxf(mx, __shfl_xor(mx, off));
    float ex = __expf(o - mx);
    float sum = ex;
    for (int off = 1; off < 16; off <<= 1) sum += __shfl_xor(sum, off);
    float r = o - mx - __logf(sum);
    if (lane < 16) out[n * CC + c] = r;
}

extern "C" void kernel_launch(void* const* d_in, const int* in_sizes, int n_in,
                              void* d_out, int out_size, void* d_ws, size_t ws_size,
                              hipStream_t stream) {
    const float* x    = (const float*)d_in[0];
    const void*  masks= d_in[1];
    const float* W    = (const float*)d_in[2];
    const float* a1   = (const float*)d_in[3];
    const float* a2   = (const float*)d_in[4];
    const float* Wout = (const float*)d_in[5];
    const float* ao1  = (const float*)d_in[6];
    const float* ao2  = (const float*)d_in[7];
    float* out = (float*)d_out;

    char* ws = (char*)d_ws;
    uint64_t* bits = (uint64_t*)ws;                         // 4 MB
    uint16_t* Whb  = (uint16_t*)(ws + (size_t)KHOP * NN * 64 * 8);  // 4 MB (bf16)
    float* f1  = (float*)(Whb + (size_t)HH * NN * DD);      // 128 KB
    float* f2  = f1 + (size_t)HH * NN;                      // 128 KB
    float* Who = f2 + (size_t)HH * NN;                      // 256 KB
    float* g1  = Who + (size_t)NN * CC;                     // 16 KB
    float* g2  = g1 + NN;                                   // 16 KB

    build_bits<<<1024, 256, 0, stream>>>((const uint32_t*)masks, bits);
    wh_gemm<<<dim3(NN / 64, HH), 256, 0, stream>>>(x, W, a1, a2, Whb, f1, f2);
    attn1<<<NN, 512, 0, stream>>>(bits, Whb, f1, f2, Wout, ao1, ao2, Who, g1, g2);
    attn2<<<NN / 4, 256, 0, stream>>>(bits, Who, g1, g2, out);
    (void)in_sizes; (void)n_in; (void)out_size; (void)ws_size;
}

// Round 8
// 307.177 us; speedup vs baseline: 1.3385x; 1.1242x over previous
//
#include <hip/hip_runtime.h>
#include <cstdint>

#define NN 4096
#define FIN 512
#define DD 64
#define HH 8
#define CC 16
#define KHOP 2
#define ALPHA 0.2f
#define BETA 0.9f

typedef __attribute__((ext_vector_type(8))) short short8;
typedef __attribute__((ext_vector_type(4))) float floatx4;

static __device__ __forceinline__ uint16_t f2bf(float f) {  // RTNE
    uint32_t u = __float_as_uint(f);
    u += 0x7FFFu + ((u >> 16) & 1u);
    return (uint16_t)(u >> 16);
}

// nonzero-byte nibble: bit i set iff byte i of x is nonzero
static __device__ __forceinline__ uint32_t nz_nib(uint32_t x) {
    uint32_t zero80 = (x - 0x01010101u) & ~x & 0x80808080u;  // 0x80 where byte==0
    uint32_t nz80 = zero80 ^ 0x80808080u;                    // 0x80 where byte!=0
    return ((nz80 >> 7) * 0x01020408u) >> 24;                // bits 0..3
}

// ---------------- build packed bitmask: [K][N][64] u64 (probe fused) ----------------
__global__ __launch_bounds__(256) void build_bits(const uint32_t* __restrict__ mraw,
                                                  uint64_t* __restrict__ bits) {
    const int totalWords = KHOP * NN * (NN / 64);  // 524288
    const int tid = threadIdx.x;
    __shared__ int sflag;
    if (tid == 0) sflag = 1;
    __syncthreads();
    bool ok = true;
    for (int i = tid; i < 4096; i += 256) {
        uint32_t w = mraw[i];
        if (!(w == 0u || w == 1u || w == 0x3F800000u)) ok = false;
    }
    if (!ok) sflag = 0;  // benign race: all writers write 0
    __syncthreads();
    const int flag = sflag;

    const int wave_id = (blockIdx.x * 256 + tid) >> 6;  // 4096 waves
    const int lane = tid & 63;

    if (!flag) {  // 1-byte bool elements (the observed case: FETCH == 2x 33.5 MB in R6)
        const uint8_t* m8 = (const uint8_t*)mraw;
        const uint8_t* base = m8 + (size_t)wave_id * 8192 + (size_t)lane * 16;
        uint4 v[8];
#pragma unroll
        for (int i = 0; i < 8; ++i)
            v[i] = *(const uint4*)(base + (size_t)i * 1024);
        const int idx = (lane & 15) * 4;
#pragma unroll
        for (int i = 0; i < 8; ++i) {
            uint32_t m16 = nz_nib(v[i].x) | (nz_nib(v[i].y) << 4) |
                           (nz_nib(v[i].z) << 8) | (nz_nib(v[i].w) << 12);
            uint32_t u0 = (uint32_t)__shfl((int)m16, idx);
            uint32_t u1 = (uint32_t)__shfl((int)m16, idx + 1);
            uint32_t u2 = (uint32_t)__shfl((int)m16, idx + 2);
            uint32_t u3 = (uint32_t)__shfl((int)m16, idx + 3);
            if (lane < 16) {
                uint64_t wrd = (uint64_t)((u0 & 0xFFFFu) | (u1 << 16)) |
                               ((uint64_t)((u2 & 0xFFFFu) | (u3 << 16)) << 32);
                bits[(size_t)wave_id * 128 + i * 16 + lane] = wrd;
            }
        }
    } else {  // 4-byte elements: ballot path, 8-deep unroll
        const int w0b = wave_id * 128;
        for (int w0 = w0b; w0 < w0b + 128 && w0 < totalWords; w0 += 8) {
            uint32_t v[8];
#pragma unroll
            for (int i = 0; i < 8; ++i)
                v[i] = mraw[(size_t)(w0 + i) * 64 + lane];
#pragma unroll
            for (int i = 0; i < 8; ++i) {
                unsigned long long b = __ballot(v[i] != 0u);
                if (lane == 0) bits[w0 + i] = b;
            }
        }
    }
}

// ---------------- prep: Wt[h][d][k] bf16 = W[h][k][d] fp32 (transpose+cast) ----------------
__global__ __launch_bounds__(256) void prep(const float* __restrict__ W,
                                            uint16_t* __restrict__ Wt) {
    const int h = blockIdx.y, kt = blockIdx.x;  // k-tile of 64
    const int t = threadIdx.x;
    __shared__ float tile[64][65];
    {
        const int kr = t >> 4, d4 = (t & 15) * 4;
#pragma unroll
        for (int r = 0; r < 4; ++r) {
            const int k = kr + r * 16;
            float4 v = *(const float4*)&W[((size_t)h * FIN + kt * 64 + k) * DD + d4];
            tile[k][d4 + 0] = v.x; tile[k][d4 + 1] = v.y;
            tile[k][d4 + 2] = v.z; tile[k][d4 + 3] = v.w;
        }
    }
    __syncthreads();
    const int d = t >> 2, kb = (t & 3) * 16;
    uint16_t tmp[16];
#pragma unroll
    for (int i = 0; i < 16; ++i) tmp[i] = f2bf(tile[kb + i][d]);
    uint4 o0, o1;
    o0.x = tmp[0] | ((uint32_t)tmp[1] << 16);  o0.y = tmp[2] | ((uint32_t)tmp[3] << 16);
    o0.z = tmp[4] | ((uint32_t)tmp[5] << 16);  o0.w = tmp[6] | ((uint32_t)tmp[7] << 16);
    o1.x = tmp[8] | ((uint32_t)tmp[9] << 16);  o1.y = tmp[10] | ((uint32_t)tmp[11] << 16);
    o1.z = tmp[12] | ((uint32_t)tmp[13] << 16); o1.w = tmp[14] | ((uint32_t)tmp[15] << 16);
    uint16_t* dst = Wt + ((size_t)h * DD + d) * FIN + kt * 64 + kb;
    *(uint4*)dst = o0;
    *(uint4*)(dst + 8) = o1;
}

// ---------------- layer-1 GEMM via MFMA: Wh = x @ W[h], bf16 out, fused f1/f2 ----------------
// 64n x 64d tile, 4 waves (wave w: rows w*16..w*16+15), K-chunks of 64.
// LDS rows padded to 72 shorts -> frag ds_read_b128 is 2-way bank-aliased (free).
__global__ __launch_bounds__(256) void wh_gemm(const float* __restrict__ x,
                                               const uint16_t* __restrict__ Wt,
                                               const float* __restrict__ a1,
                                               const float* __restrict__ a2,
                                               uint16_t* __restrict__ Whb,
                                               float* __restrict__ f1,
                                               float* __restrict__ f2) {
    const int h = blockIdx.y;
    const int n0 = blockIdx.x * 64;
    const int tid = threadIdx.x;
    const int wave = tid >> 6, lane = tid & 63;
    const int q = lane >> 4, r = lane & 15;
    __shared__ uint16_t xs[64 * 72];  // 9.2 KB
    __shared__ uint16_t ws[64 * 72];  // 9.2 KB
    floatx4 acc[4] = {floatx4{0,0,0,0}, floatx4{0,0,0,0}, floatx4{0,0,0,0}, floatx4{0,0,0,0}};

    for (int chunk = 0; chunk < 8; ++chunk) {
        const int fc = chunk * 64;
        {   // stage x: 64 rows x 64 k fp32 -> bf16
            const int row = tid >> 4, c4 = (tid & 15) * 4;
#pragma unroll
            for (int rr = 0; rr < 4; ++rr) {
                const int n = row + rr * 16;
                float4 v = *(const float4*)&x[(size_t)(n0 + n) * FIN + fc + c4];
                ushort4 o;
                o.x = f2bf(v.x); o.y = f2bf(v.y); o.z = f2bf(v.z); o.w = f2bf(v.w);
                *(ushort4*)&xs[n * 72 + c4] = o;
            }
            // stage Wt: 64 d-rows x 64 shorts (already bf16, k-contiguous)
            const int d = tid >> 2, kb = (tid & 3) * 16;
            const uint16_t* src = Wt + ((size_t)h * DD + d) * FIN + fc + kb;
            uint4 w0 = *(const uint4*)src;
            uint4 w1 = *(const uint4*)(src + 8);
            *(uint4*)&ws[d * 72 + kb] = w0;
            *(uint4*)&ws[d * 72 + kb + 8] = w1;
        }
        __syncthreads();
        const int mrow = wave * 16 + r;
        short8 a0 = *(const short8*)&xs[mrow * 72 + q * 8];
        short8 a1f = *(const short8*)&xs[mrow * 72 + 32 + q * 8];
#pragma unroll
        for (int t = 0; t < 4; ++t) {
            short8 b0 = *(const short8*)&ws[(t * 16 + r) * 72 + q * 8];
            short8 b1 = *(const short8*)&ws[(t * 16 + r) * 72 + 32 + q * 8];
            acc[t] = __builtin_amdgcn_mfma_f32_16x16x32_bf16(a0, b0, acc[t], 0, 0, 0);
            acc[t] = __builtin_amdgcn_mfma_f32_16x16x32_bf16(a1f, b1, acc[t], 0, 0, 0);
        }
        __syncthreads();
    }

    // C layout (m89-verified): element (m, d): m = wave*16 + q*4 + reg, d = t*16 + r
#pragma unroll
    for (int t = 0; t < 4; ++t) {
#pragma unroll
        for (int reg = 0; reg < 4; ++reg) {
            const int m = wave * 16 + q * 4 + reg;
            const int d = t * 16 + r;
            Whb[((size_t)h * NN + n0 + m) * DD + d] = f2bf(acc[t][reg]);
        }
    }
    // f1/f2: per reg, sum over t (VGPR) then over r (quad shfl)
    float a1r[4], a2r[4];
#pragma unroll
    for (int t = 0; t < 4; ++t) {
        a1r[t] = a1[h * DD + t * 16 + r];
        a2r[t] = a2[h * DD + t * 16 + r];
    }
#pragma unroll
    for (int reg = 0; reg < 4; ++reg) {
        float p1 = 0.f, p2 = 0.f;
#pragma unroll
        for (int t = 0; t < 4; ++t) {
            p1 += acc[t][reg] * a1r[t];
            p2 += acc[t][reg] * a2r[t];
        }
#pragma unroll
        for (int off = 1; off < 16; off <<= 1) {
            p1 += __shfl_xor(p1, off);
            p2 += __shfl_xor(p2, off);
        }
        if (r == 0) {
            const int m = wave * 16 + q * 4 + reg;
            f1[h * NN + n0 + m] = p1;
            f2[h * NN + n0 + m] = p2;
        }
    }
}

// ---------------- layer-1 attention + fused output GEMM ----------------
__global__ __launch_bounds__(512) void attn1(const uint64_t* __restrict__ bits,
                                             const uint16_t* __restrict__ Whb,
                                             const float* __restrict__ f1,
                                             const float* __restrict__ f2,
                                             const float* __restrict__ Wout,
                                             const float* __restrict__ ao1,
                                             const float* __restrict__ ao2,
                                             float* __restrict__ Who,
                                             float* __restrict__ g1,
                                             float* __restrict__ g2) {
    const int n = blockIdx.x;
    const int tid = threadIdx.x;
    const int h = tid >> 6, lane = tid & 63;
    const int hl = lane & 31, uh = lane >> 5;
    __shared__ uint16_t nbr[KHOP][NN];
    __shared__ float xrow[HH * DD];
    __shared__ float part[32][17];
    __shared__ int cnt[KHOP];
    if (h < KHOP) {
        const int hop = h;
        if (lane == 0) cnt[hop] = 0;
        uint64_t v = bits[((size_t)hop * NN + n) * 64 + lane];
        int c = __popcll(v);
        int base = 0;
        if (c) base = atomicAdd(&cnt[hop], c);
        int mb = lane * 64;
        while (v) {
            int j = __ffsll((unsigned long long)v) - 1;
            nbr[hop][base++] = (uint16_t)(mb + j);
            v &= v - 1;
        }
    }
    const float f1n = f1[h * NN + n];
    const float* __restrict__ f2h = f2 + h * NN;
    const char* gbase = (const char*)(Whb + (size_t)h * NN * DD) + hl * 4;
    __syncthreads();
    float res0 = 0.f, res1 = 0.f;
    for (int hop = 0; hop < KHOP; ++hop) {
        const int count = cnt[hop];
        const uint16_t* __restrict__ nb = nbr[hop];
        float acc0 = 0.f, acc1 = 0.f, denp = 0.f;
        for (int b0 = 0; b0 < count; b0 += 64) {
            const int bs = min(64, count - b0);
            uint32_t moff = 0u; float w = 0.f;
            if (lane < bs) {
                int m = nb[b0 + lane];
                float e = f1n + f2h[m];
                e = (e > 0.f) ? e : ALPHA * e;
                w = __expf(e);
                moff = (uint32_t)m << 7;
            }
            denp += w;
            const int nch = (bs + 15) >> 4;
            for (int c0 = 0; c0 < nch; ++c0) {
                const int jb = c0 << 4;
#pragma unroll
                for (int p = 0; p < 8; ++p) {
                    const int j = jb + 2 * p;
                    const uint32_t wu0 = __builtin_amdgcn_readlane(__float_as_uint(w), j);
                    const uint32_t wu1 = __builtin_amdgcn_readlane(__float_as_uint(w), j + 1);
                    const uint32_t o0 = __builtin_amdgcn_readlane(moff, j);
                    const uint32_t o1 = __builtin_amdgcn_readlane(moff, j + 1);
                    const float wsel = __uint_as_float(uh ? wu1 : wu0);
                    const uint32_t osel = uh ? o1 : o0;
                    const uint32_t dv = *(const uint32_t*)(gbase + osel);
                    acc0 += wsel * __uint_as_float(dv << 16);
                    acc1 += wsel * __uint_as_float(dv & 0xFFFF0000u);
                }
            }
        }
        float den = denp;
#pragma unroll
        for (int off = 1; off < 64; off <<= 1) den += __shfl_xor(den, off);
        acc0 += __shfl_xor(acc0, 32);
        acc1 += __shfl_xor(acc1, 32);
        const float scale = ((hop == 0) ? 1.f : BETA) / den;
        res0 += scale * acc0;
        res1 += scale * acc1;
    }
    float v0 = (res0 > 0.f) ? res0 : (__expf(res0) - 1.f);
    float v1 = (res1 > 0.f) ? res1 : (__expf(res1) - 1.f);
    if (uh == 0) {
        xrow[h * DD + 2 * hl]     = v0;
        xrow[h * DD + 2 * hl + 1] = v1;
    }
    __syncthreads();
    {
        const int c = tid & 15, chunk = tid >> 4;
        float p = 0.f;
#pragma unroll
        for (int i = 0; i < 16; ++i)
            p += xrow[chunk * 16 + i] * Wout[(chunk * 16 + i) * CC + c];
        part[chunk][c] = p;
    }
    __syncthreads();
    if (tid < 16) {
        float s = 0.f;
#pragma unroll
        for (int k = 0; k < 32; ++k) s += part[k][tid];
        Who[n * CC + tid] = s;
        float p1 = s * ao1[tid];
        float p2 = s * ao2[tid];
#pragma unroll
        for (int off = 1; off < 16; off <<= 1) {
            p1 += __shfl_xor(p1, off);
            p2 += __shfl_xor(p2, off);
        }
        if (tid == 0) { g1[n] = p1; g2[n] = p2; }
    }
}

// ---------------- layer-2 attention + elu + log_softmax: one wave per node ----------------
// No block barriers: each wave owns its nbr region; same-wave LDS ordering is guaranteed.
__global__ __launch_bounds__(256) void attn2(const uint64_t* __restrict__ bits,
                                             const float* __restrict__ Who,
                                             const float* __restrict__ g1,
                                             const float* __restrict__ g2,
                                             float* __restrict__ out) {
    const int wv = threadIdx.x >> 6;
    const int lane = threadIdx.x & 63;
    const int n = blockIdx.x * 4 + wv;
    __shared__ uint16_t nbr[4][NN];
    uint16_t* mynbr = nbr[wv];
    const float g1n = g1[n];
    const int c = lane & 15, s = lane >> 4;
    float res = 0.f;
    for (int hop = 0; hop < KHOP; ++hop) {
        uint64_t v = bits[((size_t)hop * NN + n) * 64 + lane];
        int cpc = __popcll(v);
        int pref = cpc;
        for (int off = 1; off < 64; off <<= 1) {
            int t = __shfl_up(pref, off);
            if (lane >= off) pref += t;
        }
        int total = __shfl(pref, 63);
        int base = pref - cpc;
        int mb = lane * 64;
        while (v) {
            int j = __ffsll((unsigned long long)v) - 1;
            mynbr[base++] = (uint16_t)(mb + j);
            v &= v - 1;
        }
        float acc = 0.f, den = 0.f;
#pragma unroll 2
        for (int j = s; j < total; j += 4) {
            int m = mynbr[j];
            float e = g1n + g2[m];
            e = (e > 0.f) ? e : ALPHA * e;
            float w = __expf(e);
            den += w;
            acc += w * Who[m * CC + c];
        }
        acc += __shfl_xor(acc, 16);
        acc += __shfl_xor(acc, 32);
        den += __shfl_xor(den, 16);
        den += __shfl_xor(den, 32);
        res += ((hop == 0) ? 1.f : BETA) * (acc / den);
    }
    float o = (res > 0.f) ? res : (__expf(res) - 1.f);
    float mx = o;
    for (int off = 1; off < 16; off <<= 1) mx = fmaxf(mx, __shfl_xor(mx, off));
    float ex = __expf(o - mx);
    float sum = ex;
    for (int off = 1; off < 16; off <<= 1) sum += __shfl_xor(sum, off);
    float r = o - mx - __logf(sum);
    if (lane < 16) out[n * CC + c] = r;
}

extern "C" void kernel_launch(void* const* d_in, const int* in_sizes, int n_in,
                              void* d_out, int out_size, void* d_ws, size_t ws_size,
                              hipStream_t stream) {
    const float* x    = (const float*)d_in[0];
    const void*  masks= d_in[1];
    const float* W    = (const float*)d_in[2];
    const float* a1   = (const float*)d_in[3];
    const float* a2   = (const float*)d_in[4];
    const float* Wout = (const float*)d_in[5];
    const float* ao1  = (const float*)d_in[6];
    const float* ao2  = (const float*)d_in[7];
    float* out = (float*)d_out;

    char* ws = (char*)d_ws;
    uint64_t* bits = (uint64_t*)ws;                         // 4 MB
    uint16_t* Whb  = (uint16_t*)(ws + (size_t)KHOP * NN * 64 * 8);  // 4 MB (bf16)
    float* f1  = (float*)(Whb + (size_t)HH * NN * DD);      // 128 KB
    float* f2  = f1 + (size_t)HH * NN;                      // 128 KB
    float* Who = f2 + (size_t)HH * NN;                      // 256 KB
    float* g1  = Who + (size_t)NN * CC;                     // 16 KB
    float* g2  = g1 + NN;                                   // 16 KB
    uint16_t* Wt = (uint16_t*)(g2 + NN);                    // 512 KB (bf16 W^T)

    build_bits<<<1024, 256, 0, stream>>>((const uint32_t*)masks, bits);
    prep<<<dim3(FIN / 64, HH), 256, 0, stream>>>(W, Wt);
    wh_gemm<<<dim3(NN / 64, HH), 256, 0, stream>>>(x, Wt, a1, a2, Whb, f1, f2);
    attn1<<<NN, 512, 0, stream>>>(bits, Whb, f1, f2, Wout, ao1, ao2, Who, g1, g2);
    attn2<<<NN / 4, 256, 0, stream>>>(bits, Who, g1, g2, out);
    (void)in_sizes; (void)n_in; (void)out_size; (void)ws_size;
}

// Round 9
// 284.700 us; speedup vs baseline: 1.4442x; 1.0789x over previous
//
#include <hip/hip_runtime.h>
#include <cstdint>

#define NN 4096
#define FIN 512
#define DD 64
#define HH 8
#define CC 16
#define KHOP 2
#define ALPHA 0.2f
#define BETA 0.9f

typedef __attribute__((ext_vector_type(8))) short short8;
typedef __attribute__((ext_vector_type(4))) float floatx4;

static __device__ __forceinline__ uint16_t f2bf(float f) {  // RTNE
    uint32_t u = __float_as_uint(f);
    u += 0x7FFFu + ((u >> 16) & 1u);
    return (uint16_t)(u >> 16);
}

// nonzero-byte nibble: bit i set iff byte i of x is nonzero
static __device__ __forceinline__ uint32_t nz_nib(uint32_t x) {
    uint32_t zero80 = (x - 0x01010101u) & ~x & 0x80808080u;  // 0x80 where byte==0
    uint32_t nz80 = zero80 ^ 0x80808080u;                    // 0x80 where byte!=0
    return ((nz80 >> 7) * 0x01020408u) >> 24;                // bits 0..3
}

// ---------------- build packed bitmask: [K][N][64] u64 (probe fused) ----------------
__global__ __launch_bounds__(256) void build_bits(const uint32_t* __restrict__ mraw,
                                                  uint64_t* __restrict__ bits) {
    const int totalWords = KHOP * NN * (NN / 64);  // 524288
    const int tid = threadIdx.x;
    __shared__ int sflag;
    if (tid == 0) sflag = 1;
    __syncthreads();
    bool ok = true;
    for (int i = tid; i < 4096; i += 256) {
        uint32_t w = mraw[i];
        if (!(w == 0u || w == 1u || w == 0x3F800000u)) ok = false;
    }
    if (!ok) sflag = 0;  // benign race: all writers write 0
    __syncthreads();
    const int flag = sflag;

    const int wave_id = (blockIdx.x * 256 + tid) >> 6;  // 4096 waves
    const int lane = tid & 63;

    if (!flag) {  // 1-byte bool elements (observed: FETCH == 2x 33.5 MB in R6)
        const uint8_t* m8 = (const uint8_t*)mraw;
        const uint8_t* base = m8 + (size_t)wave_id * 8192 + (size_t)lane * 16;
        uint4 v[8];
#pragma unroll
        for (int i = 0; i < 8; ++i)
            v[i] = *(const uint4*)(base + (size_t)i * 1024);
        const int idx = (lane & 15) * 4;
#pragma unroll
        for (int i = 0; i < 8; ++i) {
            uint32_t m16 = nz_nib(v[i].x) | (nz_nib(v[i].y) << 4) |
                           (nz_nib(v[i].z) << 8) | (nz_nib(v[i].w) << 12);
            uint32_t u0 = (uint32_t)__shfl((int)m16, idx);
            uint32_t u1 = (uint32_t)__shfl((int)m16, idx + 1);
            uint32_t u2 = (uint32_t)__shfl((int)m16, idx + 2);
            uint32_t u3 = (uint32_t)__shfl((int)m16, idx + 3);
            if (lane < 16) {
                uint64_t wrd = (uint64_t)((u0 & 0xFFFFu) | (u1 << 16)) |
                               ((uint64_t)((u2 & 0xFFFFu) | (u3 << 16)) << 32);
                bits[(size_t)wave_id * 128 + i * 16 + lane] = wrd;
            }
        }
    } else {  // 4-byte elements: ballot path, 8-deep unroll
        const int w0b = wave_id * 128;
        for (int w0 = w0b; w0 < w0b + 128 && w0 < totalWords; w0 += 8) {
            uint32_t v[8];
#pragma unroll
            for (int i = 0; i < 8; ++i)
                v[i] = mraw[(size_t)(w0 + i) * 64 + lane];
#pragma unroll
            for (int i = 0; i < 8; ++i) {
                unsigned long long b = __ballot(v[i] != 0u);
                if (lane == 0) bits[w0 + i] = b;
            }
        }
    }
}

// ---------------- prep: Wt[h][d][k] bf16 = W[h][k][d] fp32 (transpose+cast) ----------------
__global__ __launch_bounds__(256) void prep(const float* __restrict__ W,
                                            uint16_t* __restrict__ Wt) {
    const int h = blockIdx.y, kt = blockIdx.x;  // k-tile of 64
    const int t = threadIdx.x;
    __shared__ float tile[64][65];
    {
        const int kr = t >> 4, d4 = (t & 15) * 4;
#pragma unroll
        for (int r = 0; r < 4; ++r) {
            const int k = kr + r * 16;
            float4 v = *(const float4*)&W[((size_t)h * FIN + kt * 64 + k) * DD + d4];
            tile[k][d4 + 0] = v.x; tile[k][d4 + 1] = v.y;
            tile[k][d4 + 2] = v.z; tile[k][d4 + 3] = v.w;
        }
    }
    __syncthreads();
    const int d = t >> 2, kb = (t & 3) * 16;
    uint16_t tmp[16];
#pragma unroll
    for (int i = 0; i < 16; ++i) tmp[i] = f2bf(tile[kb + i][d]);
    uint4 o0, o1;
    o0.x = tmp[0] | ((uint32_t)tmp[1] << 16);  o0.y = tmp[2] | ((uint32_t)tmp[3] << 16);
    o0.z = tmp[4] | ((uint32_t)tmp[5] << 16);  o0.w = tmp[6] | ((uint32_t)tmp[7] << 16);
    o1.x = tmp[8] | ((uint32_t)tmp[9] << 16);  o1.y = tmp[10] | ((uint32_t)tmp[11] << 16);
    o1.z = tmp[12] | ((uint32_t)tmp[13] << 16); o1.w = tmp[14] | ((uint32_t)tmp[15] << 16);
    uint16_t* dst = Wt + ((size_t)h * DD + d) * FIN + kt * 64 + kb;
    *(uint4*)dst = o0;
    *(uint4*)(dst + 8) = o1;
}

// ---------------- layer-1 GEMM via MFMA: Wh = x @ W[h], bf16 out, fused f1/f2 ----------------
__global__ __launch_bounds__(256) void wh_gemm(const float* __restrict__ x,
                                               const uint16_t* __restrict__ Wt,
                                               const float* __restrict__ a1,
                                               const float* __restrict__ a2,
                                               uint16_t* __restrict__ Whb,
                                               float* __restrict__ f1,
                                               float* __restrict__ f2) {
    const int h = blockIdx.y;
    const int n0 = blockIdx.x * 64;
    const int tid = threadIdx.x;
    const int wave = tid >> 6, lane = tid & 63;
    const int q = lane >> 4, r = lane & 15;
    __shared__ uint16_t xs[64 * 72];
    __shared__ uint16_t ws[64 * 72];
    floatx4 acc[4] = {floatx4{0,0,0,0}, floatx4{0,0,0,0}, floatx4{0,0,0,0}, floatx4{0,0,0,0}};

    for (int chunk = 0; chunk < 8; ++chunk) {
        const int fc = chunk * 64;
        {
            const int row = tid >> 4, c4 = (tid & 15) * 4;
#pragma unroll
            for (int rr = 0; rr < 4; ++rr) {
                const int n = row + rr * 16;
                float4 v = *(const float4*)&x[(size_t)(n0 + n) * FIN + fc + c4];
                ushort4 o;
                o.x = f2bf(v.x); o.y = f2bf(v.y); o.z = f2bf(v.z); o.w = f2bf(v.w);
                *(ushort4*)&xs[n * 72 + c4] = o;
            }
            const int d = tid >> 2, kb = (tid & 3) * 16;
            const uint16_t* src = Wt + ((size_t)h * DD + d) * FIN + fc + kb;
            uint4 w0 = *(const uint4*)src;
            uint4 w1 = *(const uint4*)(src + 8);
            *(uint4*)&ws[d * 72 + kb] = w0;
            *(uint4*)&ws[d * 72 + kb + 8] = w1;
        }
        __syncthreads();
        const int mrow = wave * 16 + r;
        short8 a0 = *(const short8*)&xs[mrow * 72 + q * 8];
        short8 a1f = *(const short8*)&xs[mrow * 72 + 32 + q * 8];
#pragma unroll
        for (int t = 0; t < 4; ++t) {
            short8 b0 = *(const short8*)&ws[(t * 16 + r) * 72 + q * 8];
            short8 b1 = *(const short8*)&ws[(t * 16 + r) * 72 + 32 + q * 8];
            acc[t] = __builtin_amdgcn_mfma_f32_16x16x32_bf16(a0, b0, acc[t], 0, 0, 0);
            acc[t] = __builtin_amdgcn_mfma_f32_16x16x32_bf16(a1f, b1, acc[t], 0, 0, 0);
        }
        __syncthreads();
    }

#pragma unroll
    for (int t = 0; t < 4; ++t) {
#pragma unroll
        for (int reg = 0; reg < 4; ++reg) {
            const int m = wave * 16 + q * 4 + reg;
            const int d = t * 16 + r;
            Whb[((size_t)h * NN + n0 + m) * DD + d] = f2bf(acc[t][reg]);
        }
    }
    float a1r[4], a2r[4];
#pragma unroll
    for (int t = 0; t < 4; ++t) {
        a1r[t] = a1[h * DD + t * 16 + r];
        a2r[t] = a2[h * DD + t * 16 + r];
    }
#pragma unroll
    for (int reg = 0; reg < 4; ++reg) {
        float p1 = 0.f, p2 = 0.f;
#pragma unroll
        for (int t = 0; t < 4; ++t) {
            p1 += acc[t][reg] * a1r[t];
            p2 += acc[t][reg] * a2r[t];
        }
#pragma unroll
        for (int off = 1; off < 16; off <<= 1) {
            p1 += __shfl_xor(p1, off);
            p2 += __shfl_xor(p2, off);
        }
        if (r == 0) {
            const int m = wave * 16 + q * 4 + reg;
            f1[h * NN + n0 + m] = p1;
            f2[h * NN + n0 + m] = p2;
        }
    }
}

// ---------------- layer-1 attention + fused output GEMM (inner loop v4) ----------------
// Per 16-edge chunk: 8 ds_read_b64 broadcasts of (w, rowoff) THEN 8 independent
// global loads at wave-uniform SGPR base + 32-bit voffset. No readlane, no 64-bit
// per-load address chain, loads 8-deep in flight.
__global__ __launch_bounds__(512) void attn1(const uint64_t* __restrict__ bits,
                                             const uint16_t* __restrict__ Whb,
                                             const float* __restrict__ f1,
                                             const float* __restrict__ f2,
                                             const float* __restrict__ Wout,
                                             const float* __restrict__ ao1,
                                             const float* __restrict__ ao2,
                                             float* __restrict__ Who,
                                             float* __restrict__ g1,
                                             float* __restrict__ g2) {
    const int n = blockIdx.x;
    const int tid = threadIdx.x;
    const int h = tid >> 6, lane = tid & 63;
    const int hl = lane & 31, uh = lane >> 5;
    __shared__ uint16_t nbr[KHOP][NN];
    __shared__ uint2 wm[HH][64];
    __shared__ float xrow[HH * DD];
    __shared__ float part[32][17];
    __shared__ int cnt[KHOP];
    if (h < KHOP) {
        const int hop = h;
        if (lane == 0) cnt[hop] = 0;
        uint64_t v = bits[((size_t)hop * NN + n) * 64 + lane];
        int c = __popcll(v);
        int base = 0;
        if (c) base = atomicAdd(&cnt[hop], c);
        int mb = lane * 64;
        while (v) {
            int j = __ffsll((unsigned long long)v) - 1;
            nbr[hop][base++] = (uint16_t)(mb + j);
            v &= v - 1;
        }
    }
    const float f1n = f1[h * NN + n];
    const float* __restrict__ f2h = f2 + h * NN;
    const uint16_t* __restrict__ hb = Whb + (size_t)h * NN * DD;  // wave-uniform base
    const uint32_t dbyte = (uint32_t)hl * 4;                      // lane's d-offset bytes
    __syncthreads();
    float res0 = 0.f, res1 = 0.f;
    for (int hop = 0; hop < KHOP; ++hop) {
        const int count = cnt[hop];
        const uint16_t* __restrict__ nb = nbr[hop];
        uint2* __restrict__ wmh = wm[h];
        float acc0 = 0.f, acc1 = 0.f, denp = 0.f;
        for (int b0 = 0; b0 < count; b0 += 64) {
            const int bs = min(64, count - b0);
            uint32_t wbits = 0u, moff = 0u;
            if (lane < bs) {
                int m = nb[b0 + lane];
                float e = f1n + f2h[m];
                e = (e > 0.f) ? e : ALPHA * e;
                float w = __expf(e);
                denp += w;
                wbits = __float_as_uint(w);
                moff = (uint32_t)m << 7;  // byte offset of 128-B bf16 row
            }
            wmh[lane] = make_uint2(wbits, moff);  // same-wave LDS: ordered, no barrier
            const int npair8 = ((((bs + 1) >> 1) + 7) & ~7);  // pairs, rounded to 8
            for (int c0 = 0; c0 < npair8; c0 += 8) {
                uint2 pw[8];
#pragma unroll
                for (int i = 0; i < 8; ++i)
                    pw[i] = wmh[2 * (c0 + i) + uh];  // broadcast per half-wave
#pragma unroll
                for (int i = 0; i < 8; ++i) {
                    const uint32_t dv =
                        *(const uint32_t*)((const char*)hb + (pw[i].y + dbyte));
                    const float w = __uint_as_float(pw[i].x);
                    acc0 += w * __uint_as_float(dv << 16);
                    acc1 += w * __uint_as_float(dv & 0xFFFF0000u);
                }
            }
        }
        float den = denp;
#pragma unroll
        for (int off = 1; off < 64; off <<= 1) den += __shfl_xor(den, off);
        acc0 += __shfl_xor(acc0, 32);
        acc1 += __shfl_xor(acc1, 32);
        const float scale = ((hop == 0) ? 1.f : BETA) / den;
        res0 += scale * acc0;
        res1 += scale * acc1;
    }
    float v0 = (res0 > 0.f) ? res0 : (__expf(res0) - 1.f);
    float v1 = (res1 > 0.f) ? res1 : (__expf(res1) - 1.f);
    if (uh == 0) {
        xrow[h * DD + 2 * hl]     = v0;
        xrow[h * DD + 2 * hl + 1] = v1;
    }
    __syncthreads();
    {
        const int c = tid & 15, chunk = tid >> 4;
        float p = 0.f;
#pragma unroll
        for (int i = 0; i < 16; ++i)
            p += xrow[chunk * 16 + i] * Wout[(chunk * 16 + i) * CC + c];
        part[chunk][c] = p;
    }
    __syncthreads();
    if (tid < 16) {
        float s = 0.f;
#pragma unroll
        for (int k = 0; k < 32; ++k) s += part[k][tid];
        Who[n * CC + tid] = s;
        float p1 = s * ao1[tid];
        float p2 = s * ao2[tid];
#pragma unroll
        for (int off = 1; off < 16; off <<= 1) {
            p1 += __shfl_xor(p1, off);
            p2 += __shfl_xor(p2, off);
        }
        if (tid == 0) { g1[n] = p1; g2[n] = p2; }
    }
}

// ---------------- layer-2 attention + elu + log_softmax: one wave per node ----------------
__global__ __launch_bounds__(256) void attn2(const uint64_t* __restrict__ bits,
                                             const float* __restrict__ Who,
                                             const float* __restrict__ g1,
                                             const float* __restrict__ g2,
                                             float* __restrict__ out) {
    const int wv = threadIdx.x >> 6;
    const int lane = threadIdx.x & 63;
    const int n = blockIdx.x * 4 + wv;
    __shared__ uint16_t nbr[4][NN];
    uint16_t* mynbr = nbr[wv];
    const float g1n = g1[n];
    const int c = lane & 15, s = lane >> 4;
    float res = 0.f;
    for (int hop = 0; hop < KHOP; ++hop) {
        uint64_t v = bits[((size_t)hop * NN + n) * 64 + lane];
        int cpc = __popcll(v);
        int pref = cpc;
        for (int off = 1; off < 64; off <<= 1) {
            int t = __shfl_up(pref, off);
            if (lane >= off) pref += t;
        }
        int total = __shfl(pref, 63);
        int base = pref - cpc;
        int mb = lane * 64;
        while (v) {
            int j = __ffsll((unsigned long long)v) - 1;
            mynbr[base++] = (uint16_t)(mb + j);
            v &= v - 1;
        }
        float acc = 0.f, den = 0.f;
#pragma unroll 2
        for (int j = s; j < total; j += 4) {
            int m = mynbr[j];
            float e = g1n + g2[m];
            e = (e > 0.f) ? e : ALPHA * e;
            float w = __expf(e);
            den += w;
            acc += w * Who[m * CC + c];
        }
        acc += __shfl_xor(acc, 16);
        acc += __shfl_xor(acc, 32);
        den += __shfl_xor(den, 16);
        den += __shfl_xor(den, 32);
        res += ((hop == 0) ? 1.f : BETA) * (acc / den);
    }
    float o = (res > 0.f) ? res : (__expf(res) - 1.f);
    float mx = o;
    for (int off = 1; off < 16; off <<= 1) mx = fmaxf(mx, __shfl_xor(mx, off));
    float ex = __expf(o - mx);
    float sum = ex;
    for (int off = 1; off < 16; off <<= 1) sum += __shfl_xor(sum, off);
    float r = o - mx - __logf(sum);
    if (lane < 16) out[n * CC + c] = r;
}

extern "C" void kernel_launch(void* const* d_in, const int* in_sizes, int n_in,
                              void* d_out, int out_size, void* d_ws, size_t ws_size,
                              hipStream_t stream) {
    const float* x    = (const float*)d_in[0];
    const void*  masks= d_in[1];
    const float* W    = (const float*)d_in[2];
    const float* a1   = (const float*)d_in[3];
    const float* a2   = (const float*)d_in[4];
    const float* Wout = (const float*)d_in[5];
    const float* ao1  = (const float*)d_in[6];
    const float* ao2  = (const float*)d_in[7];
    float* out = (float*)d_out;

    char* ws = (char*)d_ws;
    uint64_t* bits = (uint64_t*)ws;                         // 4 MB
    uint16_t* Whb  = (uint16_t*)(ws + (size_t)KHOP * NN * 64 * 8);  // 4 MB (bf16)
    float* f1  = (float*)(Whb + (size_t)HH * NN * DD);      // 128 KB
    float* f2  = f1 + (size_t)HH * NN;                      // 128 KB
    float* Who = f2 + (size_t)HH * NN;                      // 256 KB
    float* g1  = Who + (size_t)NN * CC;                     // 16 KB
    float* g2  = g1 + NN;                                   // 16 KB
    uint16_t* Wt = (uint16_t*)(g2 + NN);                    // 512 KB (bf16 W^T)

    build_bits<<<1024, 256, 0, stream>>>((const uint32_t*)masks, bits);
    prep<<<dim3(FIN / 64, HH), 256, 0, stream>>>(W, Wt);
    wh_gemm<<<dim3(NN / 64, HH), 256, 0, stream>>>(x, Wt, a1, a2, Whb, f1, f2);
    attn1<<<NN, 512, 0, stream>>>(bits, Whb, f1, f2, Wout, ao1, ao2, Who, g1, g2);
    attn2<<<NN / 4, 256, 0, stream>>>(bits, Who, g1, g2, out);
    (void)in_sizes; (void)n_in; (void)out_size; (void)ws_size;
}

// Round 11
// 281.508 us; speedup vs baseline: 1.4606x; 1.0113x over previous
//
#include <hip/hip_runtime.h>
#include <cstdint>

#define NN 4096
#define FIN 512
#define DD 64
#define HH 8
#define CC 16
#define KHOP 2
#define ALPHA 0.2f
#define BETA 0.9f

typedef __attribute__((ext_vector_type(8))) short short8;
typedef __attribute__((ext_vector_type(4))) float floatx4;

static __device__ __forceinline__ uint16_t f2bf(float f) {  // RTNE
    uint32_t u = __float_as_uint(f);
    u += 0x7FFFu + ((u >> 16) & 1u);
    return (uint16_t)(u >> 16);
}

// nonzero-byte nibble: bit i set iff byte i of x is nonzero
static __device__ __forceinline__ uint32_t nz_nib(uint32_t x) {
    uint32_t zero80 = (x - 0x01010101u) & ~x & 0x80808080u;  // 0x80 where byte==0
    uint32_t nz80 = zero80 ^ 0x80808080u;                    // 0x80 where byte!=0
    return ((nz80 >> 7) * 0x01020408u) >> 24;                // bits 0..3
}

// ---------------- fused: build bitmask (blocks 0..1023) + W transpose (blocks 1024..1087) ----
__global__ __launch_bounds__(256) void bits_prep(const uint32_t* __restrict__ mraw,
                                                 uint64_t* __restrict__ bits,
                                                 const float* __restrict__ W,
                                                 uint16_t* __restrict__ Wt) {
    const int tid = threadIdx.x;
    if (blockIdx.x >= 1024) {  // ---- prep: Wt[h][d][k] = bf16(W[h][k][d]) ----
        const int b = blockIdx.x - 1024;
        const int h = b >> 3, kt = b & 7;
        __shared__ float tile[64][65];
        {
            const int kr = tid >> 4, d4 = (tid & 15) * 4;
#pragma unroll
            for (int r = 0; r < 4; ++r) {
                const int k = kr + r * 16;
                float4 v = *(const float4*)&W[((size_t)h * FIN + kt * 64 + k) * DD + d4];
                tile[k][d4 + 0] = v.x; tile[k][d4 + 1] = v.y;
                tile[k][d4 + 2] = v.z; tile[k][d4 + 3] = v.w;
            }
        }
        __syncthreads();
        const int d = tid >> 2, kb = (tid & 3) * 16;
        uint16_t tmp[16];
#pragma unroll
        for (int i = 0; i < 16; ++i) tmp[i] = f2bf(tile[kb + i][d]);
        uint4 o0, o1;
        o0.x = tmp[0] | ((uint32_t)tmp[1] << 16);  o0.y = tmp[2] | ((uint32_t)tmp[3] << 16);
        o0.z = tmp[4] | ((uint32_t)tmp[5] << 16);  o0.w = tmp[6] | ((uint32_t)tmp[7] << 16);
        o1.x = tmp[8] | ((uint32_t)tmp[9] << 16);  o1.y = tmp[10] | ((uint32_t)tmp[11] << 16);
        o1.z = tmp[12] | ((uint32_t)tmp[13] << 16); o1.w = tmp[14] | ((uint32_t)tmp[15] << 16);
        uint16_t* dst = Wt + ((size_t)h * DD + d) * FIN + kt * 64 + kb;
        *(uint4*)dst = o0;
        *(uint4*)(dst + 8) = o1;
        return;
    }
    // ---- build_bits ----
    const int totalWords = KHOP * NN * (NN / 64);  // 524288
    __shared__ int sflag;
    if (tid == 0) sflag = 1;
    __syncthreads();
    bool ok = true;
    for (int i = tid; i < 4096; i += 256) {
        uint32_t w = mraw[i];
        if (!(w == 0u || w == 1u || w == 0x3F800000u)) ok = false;
    }
    if (!ok) sflag = 0;  // benign race: all writers write 0
    __syncthreads();
    const int flag = sflag;

    const int wave_id = (blockIdx.x * 256 + tid) >> 6;  // 4096 waves
    const int lane = tid & 63;

    if (!flag) {  // 1-byte bool elements (observed case)
        const uint8_t* m8 = (const uint8_t*)mraw;
        const uint8_t* base = m8 + (size_t)wave_id * 8192 + (size_t)lane * 16;
        uint4 v[8];
#pragma unroll
        for (int i = 0; i < 8; ++i)
            v[i] = *(const uint4*)(base + (size_t)i * 1024);
        const int idx = (lane & 15) * 4;
#pragma unroll
        for (int i = 0; i < 8; ++i) {
            uint32_t m16 = nz_nib(v[i].x) | (nz_nib(v[i].y) << 4) |
                           (nz_nib(v[i].z) << 8) | (nz_nib(v[i].w) << 12);
            uint32_t u0 = (uint32_t)__shfl((int)m16, idx);
            uint32_t u1 = (uint32_t)__shfl((int)m16, idx + 1);
            uint32_t u2 = (uint32_t)__shfl((int)m16, idx + 2);
            uint32_t u3 = (uint32_t)__shfl((int)m16, idx + 3);
            if (lane < 16) {
                uint64_t wrd = (uint64_t)((u0 & 0xFFFFu) | (u1 << 16)) |
                               ((uint64_t)((u2 & 0xFFFFu) | (u3 << 16)) << 32);
                bits[(size_t)wave_id * 128 + i * 16 + lane] = wrd;
            }
        }
    } else {  // 4-byte elements: ballot path
        const int w0b = wave_id * 128;
        for (int w0 = w0b; w0 < w0b + 128 && w0 < totalWords; w0 += 8) {
            uint32_t v[8];
#pragma unroll
            for (int i = 0; i < 8; ++i)
                v[i] = mraw[(size_t)(w0 + i) * 64 + lane];
#pragma unroll
            for (int i = 0; i < 8; ++i) {
                unsigned long long b = __ballot(v[i] != 0u);
                if (lane == 0) bits[w0 + i] = b;
            }
        }
    }
}

// ---------------- layer-1 GEMM via MFMA: Wh = x @ W[h], bf16 out, fused f1/f2 ----------------
__global__ __launch_bounds__(256) void wh_gemm(const float* __restrict__ x,
                                               const uint16_t* __restrict__ Wt,
                                               const float* __restrict__ a1,
                                               const float* __restrict__ a2,
                                               uint16_t* __restrict__ Whb,
                                               float* __restrict__ f1,
                                               float* __restrict__ f2) {
    const int h = blockIdx.y;
    const int n0 = blockIdx.x * 64;
    const int tid = threadIdx.x;
    const int wave = tid >> 6, lane = tid & 63;
    const int q = lane >> 4, r = lane & 15;
    __shared__ uint16_t xs[64 * 72];
    __shared__ uint16_t ws[64 * 72];
    floatx4 acc[4] = {floatx4{0,0,0,0}, floatx4{0,0,0,0}, floatx4{0,0,0,0}, floatx4{0,0,0,0}};

    for (int chunk = 0; chunk < 8; ++chunk) {
        const int fc = chunk * 64;
        {
            const int row = tid >> 4, c4 = (tid & 15) * 4;
#pragma unroll
            for (int rr = 0; rr < 4; ++rr) {
                const int n = row + rr * 16;
                float4 v = *(const float4*)&x[(size_t)(n0 + n) * FIN + fc + c4];
                ushort4 o;
                o.x = f2bf(v.x); o.y = f2bf(v.y); o.z = f2bf(v.z); o.w = f2bf(v.w);
                *(ushort4*)&xs[n * 72 + c4] = o;
            }
            const int d = tid >> 2, kb = (tid & 3) * 16;
            const uint16_t* src = Wt + ((size_t)h * DD + d) * FIN + fc + kb;
            uint4 w0 = *(const uint4*)src;
            uint4 w1 = *(const uint4*)(src + 8);
            *(uint4*)&ws[d * 72 + kb] = w0;
            *(uint4*)&ws[d * 72 + kb + 8] = w1;
        }
        __syncthreads();
        const int mrow = wave * 16 + r;
        short8 a0 = *(const short8*)&xs[mrow * 72 + q * 8];
        short8 a1f = *(const short8*)&xs[mrow * 72 + 32 + q * 8];
#pragma unroll
        for (int t = 0; t < 4; ++t) {
            short8 b0 = *(const short8*)&ws[(t * 16 + r) * 72 + q * 8];
            short8 b1 = *(const short8*)&ws[(t * 16 + r) * 72 + 32 + q * 8];
            acc[t] = __builtin_amdgcn_mfma_f32_16x16x32_bf16(a0, b0, acc[t], 0, 0, 0);
            acc[t] = __builtin_amdgcn_mfma_f32_16x16x32_bf16(a1f, b1, acc[t], 0, 0, 0);
        }
        __syncthreads();
    }

#pragma unroll
    for (int t = 0; t < 4; ++t) {
#pragma unroll
        for (int reg = 0; reg < 4; ++reg) {
            const int m = wave * 16 + q * 4 + reg;
            const int d = t * 16 + r;
            Whb[((size_t)h * NN + n0 + m) * DD + d] = f2bf(acc[t][reg]);
        }
    }
    float a1r[4], a2r[4];
#pragma unroll
    for (int t = 0; t < 4; ++t) {
        a1r[t] = a1[h * DD + t * 16 + r];
        a2r[t] = a2[h * DD + t * 16 + r];
    }
#pragma unroll
    for (int reg = 0; reg < 4; ++reg) {
        float p1 = 0.f, p2 = 0.f;
#pragma unroll
        for (int t = 0; t < 4; ++t) {
            p1 += acc[t][reg] * a1r[t];
            p2 += acc[t][reg] * a2r[t];
        }
#pragma unroll
        for (int off = 1; off < 16; off <<= 1) {
            p1 += __shfl_xor(p1, off);
            p2 += __shfl_xor(p2, off);
        }
        if (r == 0) {
            const int m = wave * 16 + q * 4 + reg;
            f1[h * NN + n0 + m] = p1;
            f2[h * NN + n0 + m] = p2;
        }
    }
}

// ---------------- layer-1 attention + fused output GEMM (inner loop v4) ----------------
__global__ __launch_bounds__(512) void attn1(const uint64_t* __restrict__ bits,
                                             const uint16_t* __restrict__ Whb,
                                             const float* __restrict__ f1,
                                             const float* __restrict__ f2,
                                             const float* __restrict__ Wout,
                                             const float* __restrict__ ao1,
                                             const float* __restrict__ ao2,
                                             float* __restrict__ Who,
                                             float* __restrict__ g1,
                                             float* __restrict__ g2) {
    const int n = blockIdx.x;
    const int tid = threadIdx.x;
    const int h = tid >> 6, lane = tid & 63;
    const int hl = lane & 31, uh = lane >> 5;
    __shared__ uint16_t nbr[KHOP][NN];
    __shared__ uint2 wm[HH][64];
    __shared__ float xrow[HH * DD];
    __shared__ float part[32][17];
    __shared__ int cnt[KHOP];
    if (h < KHOP) {
        const int hop = h;
        if (lane == 0) cnt[hop] = 0;
        uint64_t v = bits[((size_t)hop * NN + n) * 64 + lane];
        int c = __popcll(v);
        int base = 0;
        if (c) base = atomicAdd(&cnt[hop], c);
        int mb = lane * 64;
        while (v) {
            int j = __ffsll((unsigned long long)v) - 1;
            nbr[hop][base++] = (uint16_t)(mb + j);
            v &= v - 1;
        }
    }
    const float f1n = f1[h * NN + n];
    const float* __restrict__ f2h = f2 + h * NN;
    const uint16_t* __restrict__ hb = Whb + (size_t)h * NN * DD;  // wave-uniform base
    const uint32_t dbyte = (uint32_t)hl * 4;
    __syncthreads();
    float res0 = 0.f, res1 = 0.f;
    for (int hop = 0; hop < KHOP; ++hop) {
        const int count = cnt[hop];
        const uint16_t* __restrict__ nb = nbr[hop];
        uint2* __restrict__ wmh = wm[h];
        float acc0 = 0.f, acc1 = 0.f, denp = 0.f;
        for (int b0 = 0; b0 < count; b0 += 64) {
            const int bs = min(64, count - b0);
            uint32_t wbits = 0u, moff = 0u;
            if (lane < bs) {
                int m = nb[b0 + lane];
                float e = f1n + f2h[m];
                e = (e > 0.f) ? e : ALPHA * e;
                float w = __expf(e);
                denp += w;
                wbits = __float_as_uint(w);
                moff = (uint32_t)m << 7;
            }
            wmh[lane] = make_uint2(wbits, moff);  // same-wave LDS: ordered, no barrier
            const int npair8 = ((((bs + 1) >> 1) + 7) & ~7);
            for (int c0 = 0; c0 < npair8; c0 += 8) {
                uint2 pw[8];
#pragma unroll
                for (int i = 0; i < 8; ++i)
                    pw[i] = wmh[2 * (c0 + i) + uh];
#pragma unroll
                for (int i = 0; i < 8; ++i) {
                    const uint32_t dv =
                        *(const uint32_t*)((const char*)hb + (pw[i].y + dbyte));
                    const float w = __uint_as_float(pw[i].x);
                    acc0 += w * __uint_as_float(dv << 16);
                    acc1 += w * __uint_as_float(dv & 0xFFFF0000u);
                }
            }
        }
        float den = denp;
#pragma unroll
        for (int off = 1; off < 64; off <<= 1) den += __shfl_xor(den, off);
        acc0 += __shfl_xor(acc0, 32);
        acc1 += __shfl_xor(acc1, 32);
        const float scale = ((hop == 0) ? 1.f : BETA) / den;
        res0 += scale * acc0;
        res1 += scale * acc1;
    }
    float v0 = (res0 > 0.f) ? res0 : (__expf(res0) - 1.f);
    float v1 = (res1 > 0.f) ? res1 : (__expf(res1) - 1.f);
    if (uh == 0) {
        xrow[h * DD + 2 * hl]     = v0;
        xrow[h * DD + 2 * hl + 1] = v1;
    }
    __syncthreads();
    {
        const int c = tid & 15, chunk = tid >> 4;
        float p = 0.f;
#pragma unroll
        for (int i = 0; i < 16; ++i)
            p += xrow[chunk * 16 + i] * Wout[(chunk * 16 + i) * CC + c];
        part[chunk][c] = p;
    }
    __syncthreads();
    if (tid < 16) {
        float s = 0.f;
#pragma unroll
        for (int k = 0; k < 32; ++k) s += part[k][tid];
        Who[n * CC + tid] = s;
        float p1 = s * ao1[tid];
        float p2 = s * ao2[tid];
#pragma unroll
        for (int off = 1; off < 16; off <<= 1) {
            p1 += __shfl_xor(p1, off);
            p2 += __shfl_xor(p2, off);
        }
        if (tid == 0) { g1[n] = p1; g2[n] = p2; }
    }
}

// ---------------- layer-2 attention + elu + log_softmax (inner loop v2, precedence fixed) ----
__global__ __launch_bounds__(256) void attn2(const uint64_t* __restrict__ bits,
                                             const float* __restrict__ Who,
                                             const float* __restrict__ g1,
                                             const float* __restrict__ g2,
                                             float* __restrict__ out) {
    const int wv = threadIdx.x >> 6;
    const int lane = threadIdx.x & 63;
    const int n = blockIdx.x * 4 + wv;
    __shared__ uint16_t nbr[4][NN];
    uint16_t* mynbr = nbr[wv];
    const float g1n = g1[n];
    const int c = lane & 15, s = lane >> 4;
    const uint32_t cbyte = (uint32_t)c * 4;
    float res = 0.f;
    for (int hop = 0; hop < KHOP; ++hop) {
        uint64_t v = bits[((size_t)hop * NN + n) * 64 + lane];
        int cpc = __popcll(v);
        int pref = cpc;
        for (int off = 1; off < 64; off <<= 1) {
            int t = __shfl_up(pref, off);
            if (lane >= off) pref += t;
        }
        int total = __shfl(pref, 63);
        int base = pref - cpc;
        int mb = lane * 64;
        while (v) {
            int j = __ffsll((unsigned long long)v) - 1;
            mynbr[base++] = (uint16_t)(mb + j);
            v &= v - 1;
        }
        float acc = 0.f, denp = 0.f;
        for (int b0 = 0; b0 < total; b0 += 64) {
            const int bs = min(64, total - b0);
            float w = 0.f; uint32_t moff = 0u;
            if (lane < bs) {
                int m = mynbr[b0 + lane];
                float e = g1n + g2[m];
                e = (e > 0.f) ? e : ALPHA * e;
                w = __expf(e);
                moff = (uint32_t)m << 6;  // fp32 row of 16 floats = 64 B
            }
            denp += w;
            const int nit = (((bs + 3) >> 2) + 1) & ~1;  // ceil(bs/4), rounded up to 2
#pragma unroll 2
            for (int i = 0; i < nit; ++i) {
                const int j = 4 * i + s;   // j<64 always; pad lanes give w=0/moff=0
                const float wj = __shfl(w, j);
                const uint32_t oj = (uint32_t)__shfl((int)moff, j);
                const float v2 = *(const float*)((const char*)Who + (oj + cbyte));
                acc += wj * v2;
            }
        }
        float den = denp;
#pragma unroll
        for (int off = 1; off < 64; off <<= 1) den += __shfl_xor(den, off);
        acc += __shfl_xor(acc, 16);
        acc += __shfl_xor(acc, 32);
        res += ((hop == 0) ? 1.f : BETA) * (acc / den);
    }
    float o = (res > 0.f) ? res : (__expf(res) - 1.f);
    float mx = o;
    for (int off = 1; off < 16; off <<= 1) mx = fmaxf(mx, __shfl_xor(mx, off));
    float ex = __expf(o - mx);
    float sum = ex;
    for (int off = 1; off < 16; off <<= 1) sum += __shfl_xor(sum, off);
    float r = o - mx - __logf(sum);
    if (lane < 16) out[n * CC + c] = r;
}

extern "C" void kernel_launch(void* const* d_in, const int* in_sizes, int n_in,
                              void* d_out, int out_size, void* d_ws, size_t ws_size,
                              hipStream_t stream) {
    const float* x    = (const float*)d_in[0];
    const void*  masks= d_in[1];
    const float* W    = (const float*)d_in[2];
    const float* a1   = (const float*)d_in[3];
    const float* a2   = (const float*)d_in[4];
    const float* Wout = (const float*)d_in[5];
    const float* ao1  = (const float*)d_in[6];
    const float* ao2  = (const float*)d_in[7];
    float* out = (float*)d_out;

    char* ws = (char*)d_ws;
    uint64_t* bits = (uint64_t*)ws;                         // 4 MB
    uint16_t* Whb  = (uint16_t*)(ws + (size_t)KHOP * NN * 64 * 8);  // 4 MB (bf16)
    float* f1  = (float*)(Whb + (size_t)HH * NN * DD);      // 128 KB
    float* f2  = f1 + (size_t)HH * NN;                      // 128 KB
    float* Who = f2 + (size_t)HH * NN;                      // 256 KB
    float* g1  = Who + (size_t)NN * CC;                     // 16 KB
    float* g2  = g1 + NN;                                   // 16 KB
    uint16_t* Wt = (uint16_t*)(g2 + NN);                    // 512 KB (bf16 W^T)

    bits_prep<<<1024 + HH * (FIN / 64), 256, 0, stream>>>((const uint32_t*)masks, bits, W, Wt);
    wh_gemm<<<dim3(NN / 64, HH), 256, 0, stream>>>(x, Wt, a1, a2, Whb, f1, f2);
    attn1<<<NN, 512, 0, stream>>>(bits, Whb, f1, f2, Wout, ao1, ao2, Who, g1, g2);
    attn2<<<NN / 4, 256, 0, stream>>>(bits, Who, g1, g2, out);
    (void)in_sizes; (void)n_in; (void)out_size; (void)ws_size;
}